// Round 4
// baseline (199.841 us; speedup 1.0000x reference)
//
#include <hip/hip_runtime.h>
#include <stdint.h>

// MHA forward.  Inputs FP32, output FP32.  Compute: bf16 MFMA, fp32 accumulate.
// B=2,S=2048,D=1024,H=16,HD=64.
//
// hs=16 fast path:
//   x2b : x fp32 -> xb bf16 (aliased into A2sl region)
//   t1  : Wo -> WoT; Wq/Wk/Wv cols -> WT3sl
//   k2  : xb @ WT3sl^T -> Qsl (pre-scaled 0.125*log2e) / Ksl, VTsl  [global_load_lds]
//   k3  : attn v9. All prior rounds ran at 8 waves/CU (2/SIMD) -- r3 freed LDS but
//         grid(512) capped blocks/CU at 2, occupancy never moved.  v9: 512 blocks x
//         8 waves (512 thr) = 16 waves/CU (4/SIMD).  Waves split the KEY dim:
//         grp A = waves 0-3 keys [0,32), grp B = waves 4-7 keys [32,64); each wave
//         keeps 16 q-rows.  Partial (O,l) are exact sums (no-max softmax -> no
//         rescale): B writes O^T/l to LDS scratch (dead K-dbuf), A adds + stores.
//         Balanced (tau,31-tau) pairing kept: 33 iters/block, no dispatch-order
//         assumptions.  Per-iter DS/MFMA/VALU totals unchanged -- only overlap 2x.
//   k4  : A2sl @ WoT^T + bo -> fp32 out  [global_load_lds]

typedef unsigned short u16;
typedef __attribute__((ext_vector_type(8))) short bf16x8;
typedef __attribute__((ext_vector_type(4))) float f32x4;

#define MFMA_BF16(a, b, c) __builtin_amdgcn_mfma_f32_16x16x32_bf16((a), (b), (c), 0, 0, 0)
#define QSCALE 0.18033688011112042f  // 0.125 * log2(e)

__device__ __forceinline__ u16 f2bf(float f) {  // RNE
  union { float f; unsigned int u; } x; x.f = f;
  unsigned int r = x.u + 0x7fffu + ((x.u >> 16) & 1u);
  return (u16)(r >> 16);
}
__device__ __forceinline__ bf16x8 pack8(float4 a, float4 b) {
  bf16x8 r;
  r[0] = (short)f2bf(a.x); r[1] = (short)f2bf(a.y);
  r[2] = (short)f2bf(a.z); r[3] = (short)f2bf(a.w);
  r[4] = (short)f2bf(b.x); r[5] = (short)f2bf(b.y);
  r[6] = (short)f2bf(b.z); r[7] = (short)f2bf(b.w);
  return r;
}
__device__ __forceinline__ void gload_lds16(const u16* g, u16* l) {
  __builtin_amdgcn_global_load_lds((__attribute__((address_space(1))) void*)g,
                                   (__attribute__((address_space(3))) void*)l, 16, 0, 0);
}

template <int CPR>
__device__ __forceinline__ int sw_off(int r, int c) {
  return (r * CPR + (c ^ (r & (CPR - 1)))) * 8;
}

__global__ __launch_bounds__(256) void x_to_bf16(const float* __restrict__ x,
                                                 u16* __restrict__ xb) {
  const size_t i = ((size_t)blockIdx.x * 256 + threadIdx.x) * 8;
  const float4 a = *(const float4*)&x[i];
  const float4 b = *(const float4*)&x[i + 4];
  *(bf16x8*)&xb[i] = pack8(a, b);
}

__global__ void transpose_cols(const float* __restrict__ W0, const float* __restrict__ W1,
                               const float* __restrict__ W2, u16* __restrict__ T,
                               int h0, int hsx64) {
  __shared__ u16 t[32][33];
  const int j0 = blockIdx.x * 32;
  const int g = j0 / hsx64;
  const float* W = (g == 0) ? W0 : (g == 1) ? W1 : W2;
  const int wc0 = h0 * 64 + (j0 % hsx64);
  const int k0 = blockIdx.y * 32;
  t[threadIdx.y][threadIdx.x] =
      f2bf(W[(size_t)(k0 + threadIdx.y) * 1024 + wc0 + threadIdx.x]);
  __syncthreads();
  T[(size_t)(j0 + threadIdx.y) * 1024 + k0 + threadIdx.x] = t[threadIdx.x][threadIdx.y];
}

// ---- k2/k4: C = A[M][K] @ BT[N][K]^T, 128x128 tile ----
template <int MODE, int AF32>
__global__ __launch_bounds__(256, 2) void gemm_bt(
    const void* __restrict__ Av, const u16* __restrict__ BT,
    void* __restrict__ C0v, u16* __restrict__ C1, u16* __restrict__ C2,
    const float* __restrict__ bias, int M, int N, int K, int hs, int h0) {
  __shared__ __align__(16) u16 lsA[128 * 32];
  __shared__ __align__(16) u16 lsB[128 * 32];
  const int tid = threadIdx.x, lane = tid & 63, wv = tid >> 6;
  const int quad = lane >> 4, l16 = lane & 15;
  const int m0 = blockIdx.y * 128, n0 = blockIdx.x * 128;
  const int wm = (wv >> 1) * 64, wn = (wv & 1) * 64;
  const int hs64 = hs * 64;
  f32x4 acc[4][4] = {};

  for (int k0 = 0; k0 < K; k0 += 32) {
    if constexpr (AF32) {
      bf16x8 va[2], vb[2];
#pragma unroll
      for (int c = 0; c < 2; ++c) {
        const int P = c * 256 + tid, r = P >> 2, cc = P & 3;
        const float* Af = (const float*)Av;
        const float4 a0 = *(const float4*)&Af[(size_t)(m0 + r) * K + k0 + cc * 8];
        const float4 a1 = *(const float4*)&Af[(size_t)(m0 + r) * K + k0 + cc * 8 + 4];
        va[c] = pack8(a0, a1);
        vb[c] = *(const bf16x8*)&BT[(size_t)(n0 + r) * K + k0 + cc * 8];
      }
      __syncthreads();
#pragma unroll
      for (int c = 0; c < 2; ++c) {
        const int P = c * 256 + tid, r = P >> 2, cc = P & 3;
        *(bf16x8*)&lsA[sw_off<4>(r, cc)] = va[c];
        *(bf16x8*)&lsB[sw_off<4>(r, cc)] = vb[c];
      }
      __syncthreads();
    } else {
      __syncthreads();
#pragma unroll
      for (int c = 0; c < 2; ++c) {
        const int P = c * 256 + tid, r = P >> 2;
        const int gcol = ((P & 3) ^ (r & 3)) * 8;
        gload_lds16((const u16*)Av + (size_t)(m0 + r) * K + k0 + gcol,
                    &lsA[(size_t)(c * 256 + wv * 64) * 8]);
        gload_lds16(BT + (size_t)(n0 + r) * K + k0 + gcol,
                    &lsB[(size_t)(c * 256 + wv * 64) * 8]);
      }
      __syncthreads();
    }
    bf16x8 af[4], bfr[4];
#pragma unroll
    for (int i = 0; i < 4; ++i) af[i] = *(const bf16x8*)&lsA[sw_off<4>(wm + i * 16 + l16, quad)];
#pragma unroll
    for (int j = 0; j < 4; ++j) bfr[j] = *(const bf16x8*)&lsB[sw_off<4>(wn + j * 16 + l16, quad)];
#pragma unroll
    for (int i = 0; i < 4; ++i)
#pragma unroll
      for (int j = 0; j < 4; ++j) acc[i][j] = MFMA_BF16(af[i], bfr[j], acc[i][j]);
  }

#pragma unroll
  for (int i = 0; i < 4; ++i)
#pragma unroll
    for (int j = 0; j < 4; ++j) {
      const int n = n0 + wn + j * 16 + l16;
      float bv = 0.f;
      if constexpr (MODE == 1) bv = bias[n];
#pragma unroll
      for (int r = 0; r < 4; ++r) {
        const int m = m0 + wm + i * 16 + quad * 4 + r;
        if constexpr (MODE == 3) {
          const int b = m >> 11, s = m & 2047;
          if (n < hs64) {
            ((u16*)C0v)[((size_t)b * 2048 + s) * hs64 + n] = f2bf(acc[i][j][r] * QSCALE);
          } else if (n < 2 * hs64) {
            C1[((size_t)b * 2048 + s) * hs64 + (n - hs64)] = f2bf(acc[i][j][r]);
          } else {
            const int nn = n - 2 * hs64;
            C2[((size_t)(b * hs + (nn >> 6)) * 64 + (nn & 63)) * 2048 + s] =
                f2bf(acc[i][j][r]);
          }
        } else {
          const int b = (m >= hs * 128) ? 1 : 0;
          const int rp = m - b * hs * 128;
          ((float*)C0v)[(size_t)(b * 2048 + h0 * 128 + rp) * 1024 + n] =
              acc[i][j][r] + bv;
        }
      }
    }
}

// ---- k3: attn v9 ----
// 512 thr / 8 waves.  grp = wv>>2 (key half of each 64-key tile), wq = wv&3
// (16 q-rows).  Block handles q-tiles tau=bx and 31-bx -> 33 iters, balanced.
// 40.5KB LDS, grid 512 -> 2 blocks/CU = 16 waves/CU = 4 waves/SIMD.
// Swapped QK^T per group: accs[nj] = mfma(K,Q) over the group's 32 keys;
// P packed in-reg to bf16 -> per-wave lsP[16][32] (even-XOR chunk swizzle,
// preserves b128 read contiguity); PV = 1 MFMA per 16-d block; l = mfma(ones,P).
// After the kt loop: grp B writes partial O^T (f32, XOR-swz) + l into the dead
// K-dbuf scratch; grp A adds (exact sum -- no rescale in no-max softmax),
// normalizes, stores.  K/V via global_load_lds, source pre-swizzled to match
// sw_off<8> reader layout.  XCD-chunk swizzle: 4 bh per XCD -> K/V L2-resident.
__global__ __launch_bounds__(512, 4) void attn_fwd(
    const u16* __restrict__ Qsl, const u16* __restrict__ Ksl,
    const u16* __restrict__ VTsl, u16* __restrict__ A2sl, int hs) {
  __shared__ __align__(16) u16 lsK[2][64 * 64];  // 2x8KB [key][hd], CPR=8; dead
                                                 // after kt loop -> f32 O scratch
  __shared__ __align__(16) u16 lsV[2][64 * 64];  // 2x8KB [hd][key], CPR=8
  __shared__ __align__(16) u16 lsP[8][16 * 32];  // per-wave P^T [q][key32], XOR-swz
  __shared__ __align__(16) float scrl[64];       // grp B partial l
  const int tid = threadIdx.x, lane = tid & 63, wv = tid >> 6;
  const int quad = lane >> 4, l16 = lane & 15;
  const int grp = wv >> 2;  // 0: keys [0,32), 1: keys [32,64)
  const int wq = wv & 3;    // q-row block
  const int wm = wq * 16;

  // bijective XCD-chunk swizzle (gridDim.x % 8 == 0 guaranteed by launcher)
  const int cpx = gridDim.x >> 3;
  const int w = (blockIdx.x & 7) * cpx + (blockIdx.x >> 3);
  const int bh = w >> 4;  // 0 .. 2*hs-1
  const int bx = w & 15;  // pair index 0..15

  const int b = (bh >= hs) ? 1 : 0, hh = bh - b * hs;
  const int hs64 = hs * 64;
  const u16* Qb = Qsl + (size_t)b * 2048 * hs64;
  const u16* Kb = Ksl + (size_t)b * 2048 * hs64;
  const u16* Vb = VTsl + (size_t)(b * hs + hh) * 64 * 2048;
  u16* A2b = A2sl + (size_t)(b * hs + hh) * 2048 * 64;
  u16* lsPw = &lsP[wv][0];
  float* scro = (float*)&lsK[0][0];  // 16KB: O[q][d] f32, chunk-XOR-swizzled

  bf16x8 ones;
#pragma unroll
  for (int i = 0; i < 8; ++i) ones[i] = (short)0x3F80;  // bf16 1.0

  for (int half = 0; half < 2; ++half) {
    const int qt = (half == 0) ? bx : 31 - bx;  // 64-row q-tile index
    const int q0 = qt * 64;

    bf16x8 qf[2];
#pragma unroll
    for (int ks = 0; ks < 2; ++ks)
      qf[ks] = *(const bf16x8*)&Qb[(size_t)(q0 + wm + l16) * hs64 + hh * 64 +
                                   ks * 32 + quad * 8];

    f32x4 acc_o[4] = {};
    f32x4 acc_l = {};

    __syncthreads();  // prev half's scratch reads + buffers done before tile-0 DMA
    {  // stage tile 0 -> buf 0 (1 K-chunk + 1 V-chunk per thread)
      const int r = tid >> 3, cc = (tid & 7) ^ (r & 7);
      gload_lds16(Kb + (size_t)r * hs64 + hh * 64 + cc * 8, &lsK[0][wv * 512]);
      gload_lds16(Vb + (size_t)r * 2048 + cc * 8, &lsV[0][wv * 512]);
    }

    for (int kt = 0; kt <= qt; ++kt) {
      const int k0 = kt * 64;
      const int buf = kt & 1;
      __syncthreads();  // compiler drains vmcnt -> tile kt landed; buf^1 free
      if (kt < qt) {    // DMA tile kt+1 into buf^1 behind this iter's compute
        const int k1 = k0 + 64, nb = buf ^ 1;
        const int r = tid >> 3, cc = (tid & 7) ^ (r & 7);
        gload_lds16(Kb + (size_t)(k1 + r) * hs64 + hh * 64 + cc * 8,
                    &lsK[nb][wv * 512]);
        gload_lds16(Vb + (size_t)r * 2048 + k1 + cc * 8, &lsV[nb][wv * 512]);
      }

      // S^T = K Q^T over this group's 32 keys (exp2 scale folded into Q)
      f32x4 accs[2] = {};
#pragma unroll
      for (int ks = 0; ks < 2; ++ks)
#pragma unroll
        for (int nj = 0; nj < 2; ++nj) {
          const bf16x8 kf = *(const bf16x8*)
              &lsK[buf][sw_off<8>(grp * 32 + nj * 16 + l16, ks * 4 + quad)];
          accs[nj] = MFMA_BF16(kf, qf[ks], accs[nj]);
        }

      // no-max softmax: p = exp2(s); only diagonal tile masks.
      // Lane holds keys (k0+grp*32+nj*16+quad*4+r) for q-col (q0+wm+l16).
      const bool diag = (kt == qt);
      const int grow = q0 + wm + l16;
#pragma unroll
      for (int nj = 0; nj < 2; ++nj) {
        const int keyb = k0 + grp * 32 + nj * 16 + quad * 4;
#pragma unroll
        for (int r = 0; r < 4; ++r) {
          float p = exp2f(accs[nj][r]);
          if (diag) p = (keyb + r > grow) ? 0.f : p;
          accs[nj][r] = p;
        }
        // truncation-pack 4 reg-adjacent keys -> one b64 LDS write.
        // chunk-of-4-u16 index (nj*4+quad) XOR'd with even value: keeps the
        // b128 read (2 adjacent chunks) contiguous.
        union { float f; unsigned int u; } t0, t1, t2, t3;
        t0.f = accs[nj][0]; t1.f = accs[nj][1];
        t2.f = accs[nj][2]; t3.f = accs[nj][3];
        uint2 wpk;
        wpk.x = (t0.u >> 16) | (t1.u & 0xFFFF0000u);
        wpk.y = (t2.u >> 16) | (t3.u & 0xFFFF0000u);
        const int idx =
            l16 * 32 + (((nj * 4 + quad) ^ ((l16 & 3) << 1)) << 2);
        *(uint2*)&lsPw[idx] = wpk;
      }

      // O^T += V^T P^T ; l += 1 P  (per-wave lsP: same-wave lgkmcnt dep only)
      const int pidx = l16 * 32 + ((quad ^ (l16 & 3)) << 3);
      const bf16x8 pf = *(const bf16x8*)&lsPw[pidx];
      acc_l = MFMA_BF16(ones, pf, acc_l);
#pragma unroll
      for (int njo = 0; njo < 4; ++njo) {
        const bf16x8 vf = *(const bf16x8*)
            &lsV[buf][sw_off<8>(njo * 16 + l16, grp * 4 + quad)];
        acc_o[njo] = MFMA_BF16(vf, pf, acc_o[njo]);
      }
    }

    // combine: exact partial sums (no-max softmax needs no rescale)
    __syncthreads();  // all lsK/lsV reads of the last tile done
    if (grp == 1) {
#pragma unroll
      for (int njo = 0; njo < 4; ++njo) {
        const int ch = (njo * 4 + quad) ^ l16;  // 16 chunks of 4 floats, XOR-swz
        *(f32x4*)&scro[(size_t)(wm + l16) * 64 + ch * 4] = acc_o[njo];
      }
      if (quad == 0) scrl[wm + l16] = acc_l[0];
    }
    __syncthreads();
    if (grp == 0) {
      const float inv = 1.0f / (acc_l[0] + scrl[wm + l16]);  // diag key -> l>0
#pragma unroll
      for (int njo = 0; njo < 4; ++njo) {
        const int ch = (njo * 4 + quad) ^ l16;
        const f32x4 ob = *(const f32x4*)&scro[(size_t)(wm + l16) * 64 + ch * 4];
        uint2 o;
        o.x = (unsigned)f2bf((acc_o[njo][0] + ob[0]) * inv) |
              ((unsigned)f2bf((acc_o[njo][1] + ob[1]) * inv) << 16);
        o.y = (unsigned)f2bf((acc_o[njo][2] + ob[2]) * inv) |
              ((unsigned)f2bf((acc_o[njo][3] + ob[3]) * inv) << 16);
        *(uint2*)&A2b[(size_t)(q0 + wm + l16) * 64 + njo * 16 + quad * 4] = o;
      }
    }
  }
}

// ---------------- launcher ----------------
extern "C" void kernel_launch(void* const* d_in, const int* in_sizes, int n_in,
                              void* d_out, int out_size, void* d_ws, size_t ws_size,
                              hipStream_t stream) {
  (void)in_sizes; (void)n_in; (void)out_size;
  const float* x  = (const float*)d_in[0];
  const float* Wq = (const float*)d_in[1];
  const float* Wk = (const float*)d_in[2];
  const float* Wv = (const float*)d_in[3];
  const float* Wo = (const float*)d_in[4];
  const float* bo = (const float*)d_in[5];
  float* out = (float*)d_out;
  char* ws = (char*)d_ws;
  const size_t MB = 1024 * 1024;
  const size_t KB = 1024;

  int hs = 2;
  if      (ws_size >= 2 * MB + 16 * 2432 * KB) hs = 16;
  else if (ws_size >= 2 * MB +  8 * 2432 * KB) hs = 8;
  else if (ws_size >= 2 * MB +  4 * 2432 * KB) hs = 4;

  u16* WoT   = (u16*)(ws);
  u16* Ksl   = (u16*)(ws + 2 * MB);
  u16* VTsl  = (u16*)(ws + 2 * MB + (size_t)hs *  512 * KB);
  u16* A2sl  = (u16*)(ws + 2 * MB + (size_t)hs * 1024 * KB);
  u16* WT3sl = (u16*)(ws + 2 * MB + (size_t)hs * 1536 * KB);
  u16* Qsl   = (u16*)(ws + 2 * MB + (size_t)hs * 1920 * KB);

  transpose_cols<<<dim3(32, 32), dim3(32, 32), 0, stream>>>(Wo, Wo, Wo, WoT, 0, 1024);
  if (hs == 16) {
    u16* xb = A2sl;  // aliases A2sl: consumed by k2, overwritten by k3
    x_to_bf16<<<2048, 256, 0, stream>>>(x, xb);
    transpose_cols<<<dim3(96, 32), dim3(32, 32), 0, stream>>>(Wq, Wk, Wv, WT3sl, 0, 1024);
    gemm_bt<3, 0><<<dim3(24, 32), 256, 0, stream>>>(
        (const void*)xb, WT3sl, (void*)Qsl, Ksl, VTsl, nullptr, 4096, 3072, 1024, 16, 0);
    attn_fwd<<<dim3(512), 512, 0, stream>>>(Qsl, Ksl, VTsl, A2sl, 16);
    gemm_bt<1, 0><<<dim3(8, 32), 256, 0, stream>>>(
        (const void*)A2sl, WoT, (void*)out, nullptr, nullptr, bo, 4096, 1024, 1024, 16, 0);
  } else {
    for (int h0 = 0; h0 < 16; h0 += hs) {
      transpose_cols<<<dim3(6 * hs, 32), dim3(32, 32), 0, stream>>>(Wq, Wk, Wv, WT3sl, h0, hs * 64);
      gemm_bt<3, 1><<<dim3((3 * hs) / 2, 32), 256, 0, stream>>>(
          (const void*)x, WT3sl, (void*)Qsl, Ksl, VTsl, nullptr, 4096, 3 * hs * 64, 1024, hs, h0);
      attn_fwd<<<dim3(32 * hs), 512, 0, stream>>>(Qsl, Ksl, VTsl, A2sl, hs);
      gemm_bt<1, 0><<<dim3(8, 2 * hs), 256, 0, stream>>>(
          (const void*)A2sl, WoT, (void*)out, nullptr, nullptr, bo, 2 * hs * 128, 1024, 1024, hs, h0);
    }
  }
}

// Round 5
// 198.232 us; speedup vs baseline: 1.0081x; 1.0081x over previous
//
#include <hip/hip_runtime.h>
#include <stdint.h>

// MHA forward.  Inputs FP32, output FP32.  Compute: bf16 MFMA, fp32 accumulate.
// B=2,S=2048,D=1024,H=16,HD=64.
//
// hs=16 fast path:
//   x2b : x fp32 -> xb bf16 (aliased into A2sl region)
//   t1  : Wo -> WoT; Wq/Wk/Wv cols -> WT3sl
//   k2  : xb @ WT3sl^T -> Qsl (pre-scaled 0.125*log2e) / Ksl, VTsl  [global_load_lds]
//   k3  : attn v10.  r4 proved occupancy is not the limit (2x waves -> +4%);
//         DS pipe ~80% busy is.  v10 halves DS reads per work-unit: wave covers
//         32 q-rows x 32 keys (2 q-frags), so each kf/vf b128 read feeds 2 MFMA
//         (v9: 4 waves read byte-identical kf/vf).  Block = 4 waves (2 q-waves x
//         2 key-grps) = 64 q-rows; 72 -> 40 b128 reads per block-iter, MFMA/VALU/
//         DMA unchanged.  lsP redesigned: 128B rows (2 q-rows), full 3-bit XOR ->
//         all LDS ops at structural-minimum bank aliasing (v9's 2-bit masks
//         tripled conflict cycles).  Keeps: gload_lds staging (pre-swizzled
//         source), swapped QK^T, reg-packed bf16 P, O^T=mfma(V^T,P^T),
//         l=mfma(ones,P), key-split + exact-sum combine in dead lsK, (tau,31-tau)
//         33-iter pairing, XCD-chunk swizzle, no-max exp2 softmax.
//   k4  : A2sl @ WoT^T + bo -> fp32 out  [global_load_lds]

typedef unsigned short u16;
typedef __attribute__((ext_vector_type(8))) short bf16x8;
typedef __attribute__((ext_vector_type(4))) float f32x4;

#define MFMA_BF16(a, b, c) __builtin_amdgcn_mfma_f32_16x16x32_bf16((a), (b), (c), 0, 0, 0)
#define QSCALE 0.18033688011112042f  // 0.125 * log2(e)

__device__ __forceinline__ u16 f2bf(float f) {  // RNE
  union { float f; unsigned int u; } x; x.f = f;
  unsigned int r = x.u + 0x7fffu + ((x.u >> 16) & 1u);
  return (u16)(r >> 16);
}
__device__ __forceinline__ bf16x8 pack8(float4 a, float4 b) {
  bf16x8 r;
  r[0] = (short)f2bf(a.x); r[1] = (short)f2bf(a.y);
  r[2] = (short)f2bf(a.z); r[3] = (short)f2bf(a.w);
  r[4] = (short)f2bf(b.x); r[5] = (short)f2bf(b.y);
  r[6] = (short)f2bf(b.z); r[7] = (short)f2bf(b.w);
  return r;
}
__device__ __forceinline__ void gload_lds16(const u16* g, u16* l) {
  __builtin_amdgcn_global_load_lds((__attribute__((address_space(1))) void*)g,
                                   (__attribute__((address_space(3))) void*)l, 16, 0, 0);
}

template <int CPR>
__device__ __forceinline__ int sw_off(int r, int c) {
  return (r * CPR + (c ^ (r & (CPR - 1)))) * 8;
}

__global__ __launch_bounds__(256) void x_to_bf16(const float* __restrict__ x,
                                                 u16* __restrict__ xb) {
  const size_t i = ((size_t)blockIdx.x * 256 + threadIdx.x) * 8;
  const float4 a = *(const float4*)&x[i];
  const float4 b = *(const float4*)&x[i + 4];
  *(bf16x8*)&xb[i] = pack8(a, b);
}

__global__ void transpose_cols(const float* __restrict__ W0, const float* __restrict__ W1,
                               const float* __restrict__ W2, u16* __restrict__ T,
                               int h0, int hsx64) {
  __shared__ u16 t[32][33];
  const int j0 = blockIdx.x * 32;
  const int g = j0 / hsx64;
  const float* W = (g == 0) ? W0 : (g == 1) ? W1 : W2;
  const int wc0 = h0 * 64 + (j0 % hsx64);
  const int k0 = blockIdx.y * 32;
  t[threadIdx.y][threadIdx.x] =
      f2bf(W[(size_t)(k0 + threadIdx.y) * 1024 + wc0 + threadIdx.x]);
  __syncthreads();
  T[(size_t)(j0 + threadIdx.y) * 1024 + k0 + threadIdx.x] = t[threadIdx.x][threadIdx.y];
}

// ---- k2/k4: C = A[M][K] @ BT[N][K]^T, 128x128 tile ----
template <int MODE, int AF32>
__global__ __launch_bounds__(256, 2) void gemm_bt(
    const void* __restrict__ Av, const u16* __restrict__ BT,
    void* __restrict__ C0v, u16* __restrict__ C1, u16* __restrict__ C2,
    const float* __restrict__ bias, int M, int N, int K, int hs, int h0) {
  __shared__ __align__(16) u16 lsA[128 * 32];
  __shared__ __align__(16) u16 lsB[128 * 32];
  const int tid = threadIdx.x, lane = tid & 63, wv = tid >> 6;
  const int quad = lane >> 4, l16 = lane & 15;
  const int m0 = blockIdx.y * 128, n0 = blockIdx.x * 128;
  const int wm = (wv >> 1) * 64, wn = (wv & 1) * 64;
  const int hs64 = hs * 64;
  f32x4 acc[4][4] = {};

  for (int k0 = 0; k0 < K; k0 += 32) {
    if constexpr (AF32) {
      bf16x8 va[2], vb[2];
#pragma unroll
      for (int c = 0; c < 2; ++c) {
        const int P = c * 256 + tid, r = P >> 2, cc = P & 3;
        const float* Af = (const float*)Av;
        const float4 a0 = *(const float4*)&Af[(size_t)(m0 + r) * K + k0 + cc * 8];
        const float4 a1 = *(const float4*)&Af[(size_t)(m0 + r) * K + k0 + cc * 8 + 4];
        va[c] = pack8(a0, a1);
        vb[c] = *(const bf16x8*)&BT[(size_t)(n0 + r) * K + k0 + cc * 8];
      }
      __syncthreads();
#pragma unroll
      for (int c = 0; c < 2; ++c) {
        const int P = c * 256 + tid, r = P >> 2, cc = P & 3;
        *(bf16x8*)&lsA[sw_off<4>(r, cc)] = va[c];
        *(bf16x8*)&lsB[sw_off<4>(r, cc)] = vb[c];
      }
      __syncthreads();
    } else {
      __syncthreads();
#pragma unroll
      for (int c = 0; c < 2; ++c) {
        const int P = c * 256 + tid, r = P >> 2;
        const int gcol = ((P & 3) ^ (r & 3)) * 8;
        gload_lds16((const u16*)Av + (size_t)(m0 + r) * K + k0 + gcol,
                    &lsA[(size_t)(c * 256 + wv * 64) * 8]);
        gload_lds16(BT + (size_t)(n0 + r) * K + k0 + gcol,
                    &lsB[(size_t)(c * 256 + wv * 64) * 8]);
      }
      __syncthreads();
    }
    bf16x8 af[4], bfr[4];
#pragma unroll
    for (int i = 0; i < 4; ++i) af[i] = *(const bf16x8*)&lsA[sw_off<4>(wm + i * 16 + l16, quad)];
#pragma unroll
    for (int j = 0; j < 4; ++j) bfr[j] = *(const bf16x8*)&lsB[sw_off<4>(wn + j * 16 + l16, quad)];
#pragma unroll
    for (int i = 0; i < 4; ++i)
#pragma unroll
      for (int j = 0; j < 4; ++j) acc[i][j] = MFMA_BF16(af[i], bfr[j], acc[i][j]);
  }

#pragma unroll
  for (int i = 0; i < 4; ++i)
#pragma unroll
    for (int j = 0; j < 4; ++j) {
      const int n = n0 + wn + j * 16 + l16;
      float bv = 0.f;
      if constexpr (MODE == 1) bv = bias[n];
#pragma unroll
      for (int r = 0; r < 4; ++r) {
        const int m = m0 + wm + i * 16 + quad * 4 + r;
        if constexpr (MODE == 3) {
          const int b = m >> 11, s = m & 2047;
          if (n < hs64) {
            ((u16*)C0v)[((size_t)b * 2048 + s) * hs64 + n] = f2bf(acc[i][j][r] * QSCALE);
          } else if (n < 2 * hs64) {
            C1[((size_t)b * 2048 + s) * hs64 + (n - hs64)] = f2bf(acc[i][j][r]);
          } else {
            const int nn = n - 2 * hs64;
            C2[((size_t)(b * hs + (nn >> 6)) * 64 + (nn & 63)) * 2048 + s] =
                f2bf(acc[i][j][r]);
          }
        } else {
          const int b = (m >= hs * 128) ? 1 : 0;
          const int rp = m - b * hs * 128;
          ((float*)C0v)[(size_t)(b * 2048 + h0 * 128 + rp) * 1024 + n] =
              acc[i][j][r] + bv;
        }
      }
    }
}

// ---- k3: attn v10 ----
// 256 thr / 4 waves.  wq = wv&1 (32 q-rows), grp = wv>>1 (32-key half).
// Wave = 32q x 32k: 2 q-frags j share every kf/vf read (they're q-independent).
// Block q-tile = 64 rows; pairs (bx, 31-bx) -> 33 iters, balanced; grid 512;
// ~40.3KB LDS -> 2 blocks/CU.  Per wave-iter: 4 kf + 4 vf + 2 pf b128 reads +
// 4 b64 P writes + 18 MFMA (8 QK + 8 PV + 2 l) + 32 exp2.
// lsP per wave: [16 rows][64 u16] (row = 2 q-rows, 128B), 16B-chunk XOR with
// (q>>1)&7 (full 3 bits) -> write b64 and read b128 both at structural-minimum
// bank aliasing (verified per quarter/half-wave).
// Combine: grp B writes partial O (f32, XOR-swz) + l into dead lsK; grp A adds
// (exact sum; no-max softmax has no rescale), normalizes, stores.
__global__ __launch_bounds__(256, 2) void attn_fwd(
    const u16* __restrict__ Qsl, const u16* __restrict__ Ksl,
    const u16* __restrict__ VTsl, u16* __restrict__ A2sl, int hs) {
  __shared__ __align__(16) u16 lsK[2][64 * 64];  // 2x8KB [key][hd], CPR=8; dead
                                                 // after kt loop -> f32 O scratch
  __shared__ __align__(16) u16 lsV[2][64 * 64];  // 2x8KB [hd][key], CPR=8
  __shared__ __align__(16) u16 lsP[4][16 * 64];  // per-wave P^T, 128B rows, XOR-swz
  __shared__ __align__(16) float scrl[64];       // grp B partial l
  const int tid = threadIdx.x, lane = tid & 63, wv = tid >> 6;
  const int quad = lane >> 4, l16 = lane & 15;
  const int grp = wv >> 1;  // 0: keys [0,32), 1: keys [32,64)
  const int wq = wv & 1;    // 32-row q-block

  // bijective XCD-chunk swizzle (gridDim.x % 8 == 0 guaranteed by launcher)
  const int cpx = gridDim.x >> 3;
  const int w = (blockIdx.x & 7) * cpx + (blockIdx.x >> 3);
  const int bh = w >> 4;  // 0 .. 2*hs-1
  const int bx = w & 15;  // pair index 0..15

  const int b = (bh >= hs) ? 1 : 0, hh = bh - b * hs;
  const int hs64 = hs * 64;
  const u16* Qb = Qsl + (size_t)b * 2048 * hs64;
  const u16* Kb = Ksl + (size_t)b * 2048 * hs64;
  const u16* Vb = VTsl + (size_t)(b * hs + hh) * 64 * 2048;
  u16* A2b = A2sl + (size_t)(b * hs + hh) * 2048 * 64;
  u16* lsPw = &lsP[wv][0];
  float* scro = (float*)&lsK[0][0];  // 16KB: O[q64][d64] f32, chunk-XOR-swizzled

  bf16x8 ones;
#pragma unroll
  for (int i = 0; i < 8; ++i) ones[i] = (short)0x3F80;  // bf16 1.0

  const int prow = l16 >> 1;          // lsP row sub-index / XOR mask (q>>1)&7
  const int pb0 = (l16 & 1) << 2;     // q&1 selects 32-u16 half of the 128B row

  for (int half = 0; half < 2; ++half) {
    const int qt = (half == 0) ? bx : 31 - bx;  // 64-row q-tile index
    const int q0 = qt * 64;

    bf16x8 qf[2][2];  // [j][ks]
#pragma unroll
    for (int j = 0; j < 2; ++j)
#pragma unroll
      for (int ks = 0; ks < 2; ++ks)
        qf[j][ks] = *(const bf16x8*)&Qb[(size_t)(q0 + wq * 32 + j * 16 + l16) * hs64 +
                                        hh * 64 + ks * 32 + quad * 8];

    f32x4 acc_o[2][4] = {};
    f32x4 acc_l[2] = {};

    __syncthreads();  // prev half's scratch reads + buffers done before tile-0 DMA
#pragma unroll
    for (int c = 0; c < 2; ++c) {  // stage tile 0 -> buf 0
      const int P = c * 256 + tid;
      const int r = P >> 3, cc = (P & 7) ^ (r & 7);
      gload_lds16(Kb + (size_t)r * hs64 + hh * 64 + cc * 8,
                  &lsK[0][(c * 256 + wv * 64) * 8]);
      gload_lds16(Vb + (size_t)r * 2048 + cc * 8, &lsV[0][(c * 256 + wv * 64) * 8]);
    }

    for (int kt = 0; kt <= qt; ++kt) {
      const int k0 = kt * 64;
      const int buf = kt & 1;
      __syncthreads();  // compiler drains vmcnt -> tile kt landed; buf^1 free
      if (kt < qt) {    // DMA tile kt+1 into buf^1 behind this iter's compute
        const int k1 = k0 + 64, nb = buf ^ 1;
#pragma unroll
        for (int c = 0; c < 2; ++c) {
          const int P = c * 256 + tid;
          const int r = P >> 3, cc = (P & 7) ^ (r & 7);
          gload_lds16(Kb + (size_t)(k1 + r) * hs64 + hh * 64 + cc * 8,
                      &lsK[nb][(c * 256 + wv * 64) * 8]);
          gload_lds16(Vb + (size_t)r * 2048 + k1 + cc * 8,
                      &lsV[nb][(c * 256 + wv * 64) * 8]);
        }
      }

      // S^T = K Q^T over this grp's 32 keys; each kf read feeds both q-frags
      f32x4 accs[2][2] = {};  // [j][nj]
#pragma unroll
      for (int ks = 0; ks < 2; ++ks)
#pragma unroll
        for (int nj = 0; nj < 2; ++nj) {
          const bf16x8 kf = *(const bf16x8*)
              &lsK[buf][sw_off<8>(grp * 32 + nj * 16 + l16, ks * 4 + quad)];
          accs[0][nj] = MFMA_BF16(kf, qf[0][ks], accs[0][nj]);
          accs[1][nj] = MFMA_BF16(kf, qf[1][ks], accs[1][nj]);
        }

      // no-max softmax: p = exp2(s); only diagonal tile masks.
      // Lane holds keys (k0+grp*32+nj*16+quad*4+r) for q (q0+wq*32+j*16+l16).
      const bool diag = (kt == qt);
#pragma unroll
      for (int j = 0; j < 2; ++j) {
        const int grow = q0 + wq * 32 + j * 16 + l16;
#pragma unroll
        for (int nj = 0; nj < 2; ++nj) {
          const int keyb = k0 + grp * 32 + nj * 16 + quad * 4;
#pragma unroll
          for (int r = 0; r < 4; ++r) {
            float p = exp2f(accs[j][nj][r]);
            if (diag) p = (keyb + r > grow) ? 0.f : p;
            accs[j][nj][r] = p;
          }
          // truncation-pack 4 reg-adjacent keys -> one b64 write.
          // row=(j*16+l16)>>1 (128B rows); 16B chunk = 4*(q&1)+2*nj+(quad>>1),
          // XOR'd with full 3-bit (q>>1)&7; 8B sub = quad&1.
          union { float f; unsigned int u; } t0, t1, t2, t3;
          t0.f = accs[j][nj][0]; t1.f = accs[j][nj][1];
          t2.f = accs[j][nj][2]; t3.f = accs[j][nj][3];
          uint2 wpk;
          wpk.x = (t0.u >> 16) | (t1.u & 0xFFFF0000u);
          wpk.y = (t2.u >> 16) | (t3.u & 0xFFFF0000u);
          const int row = j * 8 + prow;
          const int chunk = (pb0 + 2 * nj + (quad >> 1)) ^ prow;
          *(uint2*)&lsPw[row * 64 + chunk * 8 + (quad & 1) * 4] = wpk;
        }
      }

      // O^T += V^T P^T ; l += 1 P  (per-wave lsP: same-wave lgkmcnt dep only)
      bf16x8 pf[2];
#pragma unroll
      for (int j = 0; j < 2; ++j) {
        const int row = j * 8 + prow;
        const int chunk = (pb0 + quad) ^ prow;
        pf[j] = *(const bf16x8*)&lsPw[row * 64 + chunk * 8];
        acc_l[j] = MFMA_BF16(ones, pf[j], acc_l[j]);
      }
#pragma unroll
      for (int njo = 0; njo < 4; ++njo) {
        const bf16x8 vf = *(const bf16x8*)
            &lsV[buf][sw_off<8>(njo * 16 + l16, grp * 4 + quad)];
        acc_o[0][njo] = MFMA_BF16(vf, pf[0], acc_o[0][njo]);
        acc_o[1][njo] = MFMA_BF16(vf, pf[1], acc_o[1][njo]);
      }
    }

    // combine: exact partial sums (no-max softmax needs no rescale)
    __syncthreads();  // all lsK/lsV reads of the last tile done
    if (grp == 1) {
#pragma unroll
      for (int j = 0; j < 2; ++j) {
#pragma unroll
        for (int njo = 0; njo < 4; ++njo) {
          const int ch = (njo * 4 + quad) ^ l16;  // 16 16B-chunks/row, XOR-swz
          *(f32x4*)&scro[(size_t)(wq * 32 + j * 16 + l16) * 64 + ch * 4] =
              acc_o[j][njo];
        }
        if (quad == 0) scrl[wq * 32 + j * 16 + l16] = acc_l[j][0];
      }
    }
    __syncthreads();
    if (grp == 0) {
#pragma unroll
      for (int j = 0; j < 2; ++j) {
        const int ql = wq * 32 + j * 16 + l16;
        const float inv = 1.0f / (acc_l[j][0] + scrl[ql]);  // diag key -> l>0
#pragma unroll
        for (int njo = 0; njo < 4; ++njo) {
          const int ch = (njo * 4 + quad) ^ l16;
          const f32x4 ob = *(const f32x4*)&scro[(size_t)ql * 64 + ch * 4];
          uint2 o;
          o.x = (unsigned)f2bf((acc_o[j][njo][0] + ob[0]) * inv) |
                ((unsigned)f2bf((acc_o[j][njo][1] + ob[1]) * inv) << 16);
          o.y = (unsigned)f2bf((acc_o[j][njo][2] + ob[2]) * inv) |
                ((unsigned)f2bf((acc_o[j][njo][3] + ob[3]) * inv) << 16);
          *(uint2*)&A2b[(size_t)(q0 + ql) * 64 + njo * 16 + quad * 4] = o;
        }
      }
    }
  }
}

// ---------------- launcher ----------------
extern "C" void kernel_launch(void* const* d_in, const int* in_sizes, int n_in,
                              void* d_out, int out_size, void* d_ws, size_t ws_size,
                              hipStream_t stream) {
  (void)in_sizes; (void)n_in; (void)out_size;
  const float* x  = (const float*)d_in[0];
  const float* Wq = (const float*)d_in[1];
  const float* Wk = (const float*)d_in[2];
  const float* Wv = (const float*)d_in[3];
  const float* Wo = (const float*)d_in[4];
  const float* bo = (const float*)d_in[5];
  float* out = (float*)d_out;
  char* ws = (char*)d_ws;
  const size_t MB = 1024 * 1024;
  const size_t KB = 1024;

  int hs = 2;
  if      (ws_size >= 2 * MB + 16 * 2432 * KB) hs = 16;
  else if (ws_size >= 2 * MB +  8 * 2432 * KB) hs = 8;
  else if (ws_size >= 2 * MB +  4 * 2432 * KB) hs = 4;

  u16* WoT   = (u16*)(ws);
  u16* Ksl   = (u16*)(ws + 2 * MB);
  u16* VTsl  = (u16*)(ws + 2 * MB + (size_t)hs *  512 * KB);
  u16* A2sl  = (u16*)(ws + 2 * MB + (size_t)hs * 1024 * KB);
  u16* WT3sl = (u16*)(ws + 2 * MB + (size_t)hs * 1536 * KB);
  u16* Qsl   = (u16*)(ws + 2 * MB + (size_t)hs * 1920 * KB);

  transpose_cols<<<dim3(32, 32), dim3(32, 32), 0, stream>>>(Wo, Wo, Wo, WoT, 0, 1024);
  if (hs == 16) {
    u16* xb = A2sl;  // aliases A2sl: consumed by k2, overwritten by k3
    x_to_bf16<<<2048, 256, 0, stream>>>(x, xb);
    transpose_cols<<<dim3(96, 32), dim3(32, 32), 0, stream>>>(Wq, Wk, Wv, WT3sl, 0, 1024);
    gemm_bt<3, 0><<<dim3(24, 32), 256, 0, stream>>>(
        (const void*)xb, WT3sl, (void*)Qsl, Ksl, VTsl, nullptr, 4096, 3072, 1024, 16, 0);
    attn_fwd<<<dim3(512), 256, 0, stream>>>(Qsl, Ksl, VTsl, A2sl, 16);
    gemm_bt<1, 0><<<dim3(8, 32), 256, 0, stream>>>(
        (const void*)A2sl, WoT, (void*)out, nullptr, nullptr, bo, 4096, 1024, 1024, 16, 0);
  } else {
    for (int h0 = 0; h0 < 16; h0 += hs) {
      transpose_cols<<<dim3(6 * hs, 32), dim3(32, 32), 0, stream>>>(Wq, Wk, Wv, WT3sl, h0, hs * 64);
      gemm_bt<3, 1><<<dim3((3 * hs) / 2, 32), 256, 0, stream>>>(
          (const void*)x, WT3sl, (void*)Qsl, Ksl, VTsl, nullptr, 4096, 3 * hs * 64, 1024, hs, h0);
      attn_fwd<<<dim3(16 * 2 * hs), 256, 0, stream>>>(Qsl, Ksl, VTsl, A2sl, hs);
      gemm_bt<1, 0><<<dim3(8, 2 * hs), 256, 0, stream>>>(
          (const void*)A2sl, WoT, (void*)out, nullptr, nullptr, bo, 2 * hs * 128, 1024, 1024, hs, h0);
    }
  }
}

// Round 6
// 191.754 us; speedup vs baseline: 1.0422x; 1.0338x over previous
//
#include <hip/hip_runtime.h>
#include <stdint.h>

// MHA forward.  Inputs FP32, output FP32.  Compute: bf16 MFMA, fp32 accumulate.
// B=2,S=2048,D=1024,H=16,HD=64.
//
// hs=16 fast path (4 launches, was 6 -- inter-kernel gaps ~60us measured):
//   prep: ONE kernel = x fp32->bf16 (blocks>=128) + Wo transpose (blocks<32)
//         + Wq/Wk/Wv col transpose (blocks 32..127)
//   k2  : xb @ WT3sl^T -> Qsl (pre-scaled 0.125*log2e) / Ksl, VTsl  [global_load_lds]
//   k3  : attn v11 = v10 (wave=32q x 32keys, kf/vf shared by 2 q-frags; key-split
//         + exact-sum combine; min-alias lsP) + VALU cut: diagonal iter PEELED out
//         of the kt loop (hot body has no mask cmp/cndmask) and DMA source
//         addresses strength-reduced to pointer += tile-stride.
//         History: r2 DS -30% -> -17% time; r4 occup x2 -> +4%; r5 DS-reads -44%
//         -> null => time ~ sum of pipe busies (DS 40 + VALU 40 + MFMA 16),
//         so cut the biggest term (VALU) directly.
//   k4  : A2sl @ WoT^T + bo -> fp32 out  [global_load_lds]

typedef unsigned short u16;
typedef __attribute__((ext_vector_type(8))) short bf16x8;
typedef __attribute__((ext_vector_type(4))) float f32x4;

#define MFMA_BF16(a, b, c) __builtin_amdgcn_mfma_f32_16x16x32_bf16((a), (b), (c), 0, 0, 0)
#define QSCALE 0.18033688011112042f  // 0.125 * log2(e)

__device__ __forceinline__ u16 f2bf(float f) {  // RNE
  union { float f; unsigned int u; } x; x.f = f;
  unsigned int r = x.u + 0x7fffu + ((x.u >> 16) & 1u);
  return (u16)(r >> 16);
}
__device__ __forceinline__ bf16x8 pack8(float4 a, float4 b) {
  bf16x8 r;
  r[0] = (short)f2bf(a.x); r[1] = (short)f2bf(a.y);
  r[2] = (short)f2bf(a.z); r[3] = (short)f2bf(a.w);
  r[4] = (short)f2bf(b.x); r[5] = (short)f2bf(b.y);
  r[6] = (short)f2bf(b.z); r[7] = (short)f2bf(b.w);
  return r;
}
__device__ __forceinline__ void gload_lds16(const u16* g, u16* l) {
  __builtin_amdgcn_global_load_lds((__attribute__((address_space(1))) void*)g,
                                   (__attribute__((address_space(3))) void*)l, 16, 0, 0);
}

template <int CPR>
__device__ __forceinline__ int sw_off(int r, int c) {
  return (r * CPR + (c ^ (r & (CPR - 1)))) * 8;
}

// ---- fused prep: x->bf16 + Wo transpose + Wq/Wk/Wv transpose (hs=16 path) ----
// grid (144, 32) x block (32,32).  bx<32: Wo->WoT.  32<=bx<128: QKV->WT3sl.
// bx>=128: x2b block (bx-128)*32+by, 1024 thr x 8 elems.
__global__ __launch_bounds__(1024) void prep(
    const float* __restrict__ x, u16* __restrict__ xb,
    const float* __restrict__ Wq, const float* __restrict__ Wk,
    const float* __restrict__ Wv, const float* __restrict__ Wo,
    u16* __restrict__ WoT, u16* __restrict__ WT3) {
  const int bxg = blockIdx.x, by = blockIdx.y;
  if (bxg >= 128) {
    const int blk = (bxg - 128) * 32 + by;  // 0..511
    const int tid = threadIdx.y * 32 + threadIdx.x;
    const size_t i = ((size_t)blk * 1024 + tid) * 8;
    const float4 a = *(const float4*)&x[i];
    const float4 b2 = *(const float4*)&x[i + 4];
    *(bf16x8*)&xb[i] = pack8(a, b2);
    return;
  }
  __shared__ u16 t[32][33];
  const float* W;
  u16* T;
  int j0, wcol;
  if (bxg < 32) {
    j0 = bxg * 32; wcol = j0; W = Wo; T = WoT;
  } else {
    j0 = (bxg - 32) * 32;  // 0..3071
    const int g = j0 >> 10;
    W = (g == 0) ? Wq : (g == 1) ? Wk : Wv;
    T = WT3;
    wcol = j0 & 1023;
  }
  const int k0 = by * 32;
  t[threadIdx.y][threadIdx.x] =
      f2bf(W[(size_t)(k0 + threadIdx.y) * 1024 + wcol + threadIdx.x]);
  __syncthreads();
  T[(size_t)(j0 + threadIdx.y) * 1024 + k0 + threadIdx.x] = t[threadIdx.x][threadIdx.y];
}

// ---- fallback-path helpers (hs<16) ----
__global__ __launch_bounds__(256) void x_to_bf16(const float* __restrict__ x,
                                                 u16* __restrict__ xb) {
  const size_t i = ((size_t)blockIdx.x * 256 + threadIdx.x) * 8;
  const float4 a = *(const float4*)&x[i];
  const float4 b = *(const float4*)&x[i + 4];
  *(bf16x8*)&xb[i] = pack8(a, b);
}

__global__ void transpose_cols(const float* __restrict__ W0, const float* __restrict__ W1,
                               const float* __restrict__ W2, u16* __restrict__ T,
                               int h0, int hsx64) {
  __shared__ u16 t[32][33];
  const int j0 = blockIdx.x * 32;
  const int g = j0 / hsx64;
  const float* W = (g == 0) ? W0 : (g == 1) ? W1 : W2;
  const int wc0 = h0 * 64 + (j0 % hsx64);
  const int k0 = blockIdx.y * 32;
  t[threadIdx.y][threadIdx.x] =
      f2bf(W[(size_t)(k0 + threadIdx.y) * 1024 + wc0 + threadIdx.x]);
  __syncthreads();
  T[(size_t)(j0 + threadIdx.y) * 1024 + k0 + threadIdx.x] = t[threadIdx.x][threadIdx.y];
}

// ---- k2/k4: C = A[M][K] @ BT[N][K]^T, 128x128 tile ----
template <int MODE, int AF32>
__global__ __launch_bounds__(256, 2) void gemm_bt(
    const void* __restrict__ Av, const u16* __restrict__ BT,
    void* __restrict__ C0v, u16* __restrict__ C1, u16* __restrict__ C2,
    const float* __restrict__ bias, int M, int N, int K, int hs, int h0) {
  __shared__ __align__(16) u16 lsA[128 * 32];
  __shared__ __align__(16) u16 lsB[128 * 32];
  const int tid = threadIdx.x, lane = tid & 63, wv = tid >> 6;
  const int quad = lane >> 4, l16 = lane & 15;
  const int m0 = blockIdx.y * 128, n0 = blockIdx.x * 128;
  const int wm = (wv >> 1) * 64, wn = (wv & 1) * 64;
  const int hs64 = hs * 64;
  f32x4 acc[4][4] = {};

  for (int k0 = 0; k0 < K; k0 += 32) {
    if constexpr (AF32) {
      bf16x8 va[2], vb[2];
#pragma unroll
      for (int c = 0; c < 2; ++c) {
        const int P = c * 256 + tid, r = P >> 2, cc = P & 3;
        const float* Af = (const float*)Av;
        const float4 a0 = *(const float4*)&Af[(size_t)(m0 + r) * K + k0 + cc * 8];
        const float4 a1 = *(const float4*)&Af[(size_t)(m0 + r) * K + k0 + cc * 8 + 4];
        va[c] = pack8(a0, a1);
        vb[c] = *(const bf16x8*)&BT[(size_t)(n0 + r) * K + k0 + cc * 8];
      }
      __syncthreads();
#pragma unroll
      for (int c = 0; c < 2; ++c) {
        const int P = c * 256 + tid, r = P >> 2, cc = P & 3;
        *(bf16x8*)&lsA[sw_off<4>(r, cc)] = va[c];
        *(bf16x8*)&lsB[sw_off<4>(r, cc)] = vb[c];
      }
      __syncthreads();
    } else {
      __syncthreads();
#pragma unroll
      for (int c = 0; c < 2; ++c) {
        const int P = c * 256 + tid, r = P >> 2;
        const int gcol = ((P & 3) ^ (r & 3)) * 8;
        gload_lds16((const u16*)Av + (size_t)(m0 + r) * K + k0 + gcol,
                    &lsA[(size_t)(c * 256 + wv * 64) * 8]);
        gload_lds16(BT + (size_t)(n0 + r) * K + k0 + gcol,
                    &lsB[(size_t)(c * 256 + wv * 64) * 8]);
      }
      __syncthreads();
    }
    bf16x8 af[4], bfr[4];
#pragma unroll
    for (int i = 0; i < 4; ++i) af[i] = *(const bf16x8*)&lsA[sw_off<4>(wm + i * 16 + l16, quad)];
#pragma unroll
    for (int j = 0; j < 4; ++j) bfr[j] = *(const bf16x8*)&lsB[sw_off<4>(wn + j * 16 + l16, quad)];
#pragma unroll
    for (int i = 0; i < 4; ++i)
#pragma unroll
      for (int j = 0; j < 4; ++j) acc[i][j] = MFMA_BF16(af[i], bfr[j], acc[i][j]);
  }

#pragma unroll
  for (int i = 0; i < 4; ++i)
#pragma unroll
    for (int j = 0; j < 4; ++j) {
      const int n = n0 + wn + j * 16 + l16;
      float bv = 0.f;
      if constexpr (MODE == 1) bv = bias[n];
#pragma unroll
      for (int r = 0; r < 4; ++r) {
        const int m = m0 + wm + i * 16 + quad * 4 + r;
        if constexpr (MODE == 3) {
          const int b = m >> 11, s = m & 2047;
          if (n < hs64) {
            ((u16*)C0v)[((size_t)b * 2048 + s) * hs64 + n] = f2bf(acc[i][j][r] * QSCALE);
          } else if (n < 2 * hs64) {
            C1[((size_t)b * 2048 + s) * hs64 + (n - hs64)] = f2bf(acc[i][j][r]);
          } else {
            const int nn = n - 2 * hs64;
            C2[((size_t)(b * hs + (nn >> 6)) * 64 + (nn & 63)) * 2048 + s] =
                f2bf(acc[i][j][r]);
          }
        } else {
          const int b = (m >= hs * 128) ? 1 : 0;
          const int rp = m - b * hs * 128;
          ((float*)C0v)[(size_t)(b * 2048 + h0 * 128 + rp) * 1024 + n] =
              acc[i][j][r] + bv;
        }
      }
    }
}

// ---- k3: attn v11 ----
// 256 thr / 4 waves.  wq = wv&1 (32 q-rows), grp = wv>>1 (32-key half).
// Wave = 32q x 32k; kf/vf reads shared by 2 q-frags.  Pairs (bx, 31-bx) -> 33
// iters/block.  Diagonal iter peeled (hot body mask-free); DMA source pointers
// strength-reduced (+= tile stride).  lsP: 128B rows, full 3-bit XOR (min-alias).
// Combine: grp B writes partial O (f32) + l into dead lsK; grp A adds (exact sum,
// no-max softmax has no rescale), normalizes, stores.
__global__ __launch_bounds__(256, 2) void attn_fwd(
    const u16* __restrict__ Qsl, const u16* __restrict__ Ksl,
    const u16* __restrict__ VTsl, u16* __restrict__ A2sl, int hs) {
  __shared__ __align__(16) u16 lsK[2][64 * 64];  // dead after kt loop -> O scratch
  __shared__ __align__(16) u16 lsV[2][64 * 64];
  __shared__ __align__(16) u16 lsP[4][16 * 64];
  __shared__ __align__(16) float scrl[64];
  const int tid = threadIdx.x, lane = tid & 63, wv = tid >> 6;
  const int quad = lane >> 4, l16 = lane & 15;
  const int grp = wv >> 1, wq = wv & 1;

  // bijective XCD-chunk swizzle (gridDim.x % 8 == 0)
  const int cpx = gridDim.x >> 3;
  const int w = (blockIdx.x & 7) * cpx + (blockIdx.x >> 3);
  const int bh = w >> 4, bx = w & 15;

  const int b = (bh >= hs) ? 1 : 0, hh = bh - b * hs;
  const int hs64 = hs * 64;
  const u16* Qb = Qsl + (size_t)b * 2048 * hs64;
  const u16* Kb = Ksl + (size_t)b * 2048 * hs64;
  const u16* Vb = VTsl + (size_t)(b * hs + hh) * 64 * 2048;
  u16* A2b = A2sl + (size_t)(b * hs + hh) * 2048 * 64;
  u16* lsPw = &lsP[wv][0];
  float* scro = (float*)&lsK[0][0];

  bf16x8 ones;
#pragma unroll
  for (int i = 0; i < 8; ++i) ones[i] = (short)0x3F80;

  const int prow = l16 >> 1;       // lsP row sub-index / XOR mask
  const int pb0 = (l16 & 1) << 2;  // q&1 selects 32-u16 half of the 128B row

  // constant per-thread staging geometry (hoisted out of both loops)
  const int Pa = tid, ra = Pa >> 3, ca = (Pa & 7) ^ (ra & 7);
  const int Pb2 = 256 + tid, rb = Pb2 >> 3, cb = (Pb2 & 7) ^ (rb & 7);
  const size_t kTileStep = (size_t)64 * hs64;  // u16 elems per 64-key K tile
  const u16* const kBa = Kb + (size_t)ra * hs64 + hh * 64 + ca * 8;
  const u16* const kBb = Kb + (size_t)rb * hs64 + hh * 64 + cb * 8;
  const u16* const vBa = Vb + (size_t)ra * 2048 + ca * 8;
  const u16* const vBb = Vb + (size_t)rb * 2048 + cb * 8;
  const int dA = (wv * 64) * 8;        // LDS dest chunk a (u16 elems)
  const int dB = (256 + wv * 64) * 8;  // LDS dest chunk b

  for (int half = 0; half < 2; ++half) {
    const int qt = (half == 0) ? bx : 31 - bx;
    const int q0 = qt * 64;

    bf16x8 qf[2][2];
#pragma unroll
    for (int j = 0; j < 2; ++j)
#pragma unroll
      for (int ks = 0; ks < 2; ++ks)
        qf[j][ks] = *(const bf16x8*)&Qb[(size_t)(q0 + wq * 32 + j * 16 + l16) * hs64 +
                                        hh * 64 + ks * 32 + quad * 8];

    f32x4 acc_o[2][4] = {};
    f32x4 acc_l[2] = {};

    const u16* pkA = kBa;
    const u16* pkB = kBb;
    const u16* pvA = vBa;
    const u16* pvB = vBb;

    __syncthreads();  // prev half fully consumed before tile-0 DMA
    gload_lds16(pkA, &lsK[0][dA]);
    gload_lds16(pkB, &lsK[0][dB]);
    gload_lds16(pvA, &lsV[0][dA]);
    gload_lds16(pvB, &lsV[0][dB]);

    // one k-tile of compute; domask only at the peeled diagonal call
    auto body = [&](int buf, bool domask) {
      f32x4 accs[2][2] = {};  // [j][nj]
#pragma unroll
      for (int ks = 0; ks < 2; ++ks)
#pragma unroll
        for (int nj = 0; nj < 2; ++nj) {
          const bf16x8 kf = *(const bf16x8*)
              &lsK[buf][sw_off<8>(grp * 32 + nj * 16 + l16, ks * 4 + quad)];
          accs[0][nj] = MFMA_BF16(kf, qf[0][ks], accs[0][nj]);
          accs[1][nj] = MFMA_BF16(kf, qf[1][ks], accs[1][nj]);
        }
#pragma unroll
      for (int j = 0; j < 2; ++j) {
        const int grow = wq * 32 + j * 16 + l16;  // tile-local q row
#pragma unroll
        for (int nj = 0; nj < 2; ++nj) {
#pragma unroll
          for (int r = 0; r < 4; ++r) {
            float p = exp2f(accs[j][nj][r]);
            if (domask) {  // diagonal tile: key (tile-local) vs q (tile-local)
              const int keyb = grp * 32 + nj * 16 + quad * 4;
              p = (keyb + r > grow) ? 0.f : p;
            }
            accs[j][nj][r] = p;
          }
          union { float f; unsigned int u; } t0, t1, t2, t3;
          t0.f = accs[j][nj][0]; t1.f = accs[j][nj][1];
          t2.f = accs[j][nj][2]; t3.f = accs[j][nj][3];
          uint2 wpk;
          wpk.x = (t0.u >> 16) | (t1.u & 0xFFFF0000u);
          wpk.y = (t2.u >> 16) | (t3.u & 0xFFFF0000u);
          const int row = j * 8 + prow;
          const int chunk = (pb0 + 2 * nj + (quad >> 1)) ^ prow;
          *(uint2*)&lsPw[row * 64 + chunk * 8 + (quad & 1) * 4] = wpk;
        }
      }
      bf16x8 pf[2];
#pragma unroll
      for (int j = 0; j < 2; ++j) {
        const int row = j * 8 + prow;
        const int chunk = (pb0 + quad) ^ prow;
        pf[j] = *(const bf16x8*)&lsPw[row * 64 + chunk * 8];
        acc_l[j] = MFMA_BF16(ones, pf[j], acc_l[j]);
      }
#pragma unroll
      for (int njo = 0; njo < 4; ++njo) {
        const bf16x8 vf = *(const bf16x8*)
            &lsV[buf][sw_off<8>(njo * 16 + l16, grp * 4 + quad)];
        acc_o[0][njo] = MFMA_BF16(vf, pf[0], acc_o[0][njo]);
        acc_o[1][njo] = MFMA_BF16(vf, pf[1], acc_o[1][njo]);
      }
    };

    for (int kt = 0; kt < qt; ++kt) {  // off-diagonal: mask-free hot body
      const int buf = kt & 1, nb = buf ^ 1;
      __syncthreads();  // drains DMA of tile kt; buf^1 free
      pkA += kTileStep; pkB += kTileStep; pvA += 64; pvB += 64;
      gload_lds16(pkA, &lsK[nb][dA]);
      gload_lds16(pkB, &lsK[nb][dB]);
      gload_lds16(pvA, &lsV[nb][dA]);
      gload_lds16(pvB, &lsV[nb][dB]);
      body(buf, false);
    }
    {  // peeled diagonal tile kt == qt (no prefetch, masked)
      __syncthreads();
      body(qt & 1, true);
    }

    // combine: exact partial sums (no-max softmax needs no rescale)
    __syncthreads();  // all lsK/lsV reads of the last tile done
    if (grp == 1) {
#pragma unroll
      for (int j = 0; j < 2; ++j) {
#pragma unroll
        for (int njo = 0; njo < 4; ++njo) {
          const int ch = (njo * 4 + quad) ^ l16;
          *(f32x4*)&scro[(size_t)(wq * 32 + j * 16 + l16) * 64 + ch * 4] =
              acc_o[j][njo];
        }
        if (quad == 0) scrl[wq * 32 + j * 16 + l16] = acc_l[j][0];
      }
    }
    __syncthreads();
    if (grp == 0) {
#pragma unroll
      for (int j = 0; j < 2; ++j) {
        const int ql = wq * 32 + j * 16 + l16;
        const float inv = 1.0f / (acc_l[j][0] + scrl[ql]);  // diag key -> l>0
#pragma unroll
        for (int njo = 0; njo < 4; ++njo) {
          const int ch = (njo * 4 + quad) ^ l16;
          const f32x4 ob = *(const f32x4*)&scro[(size_t)ql * 64 + ch * 4];
          uint2 o;
          o.x = (unsigned)f2bf((acc_o[j][njo][0] + ob[0]) * inv) |
                ((unsigned)f2bf((acc_o[j][njo][1] + ob[1]) * inv) << 16);
          o.y = (unsigned)f2bf((acc_o[j][njo][2] + ob[2]) * inv) |
                ((unsigned)f2bf((acc_o[j][njo][3] + ob[3]) * inv) << 16);
          *(uint2*)&A2b[(size_t)(q0 + ql) * 64 + njo * 16 + quad * 4] = o;
        }
      }
    }
  }
}

// ---------------- launcher ----------------
extern "C" void kernel_launch(void* const* d_in, const int* in_sizes, int n_in,
                              void* d_out, int out_size, void* d_ws, size_t ws_size,
                              hipStream_t stream) {
  (void)in_sizes; (void)n_in; (void)out_size;
  const float* x  = (const float*)d_in[0];
  const float* Wq = (const float*)d_in[1];
  const float* Wk = (const float*)d_in[2];
  const float* Wv = (const float*)d_in[3];
  const float* Wo = (const float*)d_in[4];
  const float* bo = (const float*)d_in[5];
  float* out = (float*)d_out;
  char* ws = (char*)d_ws;
  const size_t MB = 1024 * 1024;
  const size_t KB = 1024;

  int hs = 2;
  if      (ws_size >= 2 * MB + 16 * 2432 * KB) hs = 16;
  else if (ws_size >= 2 * MB +  8 * 2432 * KB) hs = 8;
  else if (ws_size >= 2 * MB +  4 * 2432 * KB) hs = 4;

  u16* WoT   = (u16*)(ws);
  u16* Ksl   = (u16*)(ws + 2 * MB);
  u16* VTsl  = (u16*)(ws + 2 * MB + (size_t)hs *  512 * KB);
  u16* A2sl  = (u16*)(ws + 2 * MB + (size_t)hs * 1024 * KB);
  u16* WT3sl = (u16*)(ws + 2 * MB + (size_t)hs * 1536 * KB);
  u16* Qsl   = (u16*)(ws + 2 * MB + (size_t)hs * 1920 * KB);

  if (hs == 16) {
    u16* xb = A2sl;  // aliases A2sl: consumed by k2, overwritten by k3
    prep<<<dim3(144, 32), dim3(32, 32), 0, stream>>>(x, xb, Wq, Wk, Wv, Wo, WoT, WT3sl);
    gemm_bt<3, 0><<<dim3(24, 32), 256, 0, stream>>>(
        (const void*)xb, WT3sl, (void*)Qsl, Ksl, VTsl, nullptr, 4096, 3072, 1024, 16, 0);
    attn_fwd<<<dim3(512), 256, 0, stream>>>(Qsl, Ksl, VTsl, A2sl, 16);
    gemm_bt<1, 0><<<dim3(8, 32), 256, 0, stream>>>(
        (const void*)A2sl, WoT, (void*)out, nullptr, nullptr, bo, 4096, 1024, 1024, 16, 0);
  } else {
    transpose_cols<<<dim3(32, 32), dim3(32, 32), 0, stream>>>(Wo, Wo, Wo, WoT, 0, 1024);
    for (int h0 = 0; h0 < 16; h0 += hs) {
      transpose_cols<<<dim3(6 * hs, 32), dim3(32, 32), 0, stream>>>(Wq, Wk, Wv, WT3sl, h0, hs * 64);
      gemm_bt<3, 1><<<dim3((3 * hs) / 2, 32), 256, 0, stream>>>(
          (const void*)x, WT3sl, (void*)Qsl, Ksl, VTsl, nullptr, 4096, 3 * hs * 64, 1024, hs, h0);
      attn_fwd<<<dim3(16 * 2 * hs), 256, 0, stream>>>(Qsl, Ksl, VTsl, A2sl, hs);
      gemm_bt<1, 0><<<dim3(8, 2 * hs), 256, 0, stream>>>(
          (const void*)A2sl, WoT, (void*)out, nullptr, nullptr, bo, 2 * hs * 128, 1024, 1024, hs, h0);
    }
  }
}

// Round 7
// 185.169 us; speedup vs baseline: 1.0792x; 1.0356x over previous
//
#include <hip/hip_runtime.h>
#include <stdint.h>

// MHA forward.  Inputs FP32, output FP32.  Compute: bf16 MFMA, fp32 accumulate.
// B=2,S=2048,D=1024,H=16,HD=64.
//
// hs=16 fast path (4 launches; ~80us of wall is harness-fixed overhead, measured
// invariant to launch count -- controllable GPU time ~112us):
//   prep: x fp32->bf16 + Wo transpose + Wq/Wk/Wv col transpose (one kernel)
//   k2  : xb @ WT3sl^T -> Qsl (pre-scaled 0.125*log2e) / Ksl, VTsl
//   k3  : attn v11 (wave=32q x 32keys, kf/vf shared by 2 q-frags; key-split +
//         exact-sum combine; min-alias lsP; peeled diagonal; no-max exp2 softmax)
//   k4  : A2sl @ WoT^T + bo -> fp32 out
//
// gemm v2 (this round): k2 was 45.4us / 568 TF with MfmaUtil 22 / VALU 14 / HBM 18
// -- nothing busy => exposed DMA latency (single-buffered LDS: barrier, DMA,
// drain-barrier, compute every k-step; k4 worse at 1 block/CU).  T3-minimum:
// double-buffered LDS, stage tile kt+1 BEFORE computing kt, ONE barrier/k-step
// (its implicit vmcnt(0) drain lands after compute).  MODE3 epilogue: V-transpose
// stores packed 4xu16 -> uint2 (was 64 scattered scalar stores/thread), region
// branch hoisted per (j,lane).

typedef unsigned short u16;
typedef __attribute__((ext_vector_type(8))) short bf16x8;
typedef __attribute__((ext_vector_type(4))) float f32x4;

#define MFMA_BF16(a, b, c) __builtin_amdgcn_mfma_f32_16x16x32_bf16((a), (b), (c), 0, 0, 0)
#define QSCALE 0.18033688011112042f  // 0.125 * log2(e)

__device__ __forceinline__ u16 f2bf(float f) {  // RNE
  union { float f; unsigned int u; } x; x.f = f;
  unsigned int r = x.u + 0x7fffu + ((x.u >> 16) & 1u);
  return (u16)(r >> 16);
}
__device__ __forceinline__ bf16x8 pack8(float4 a, float4 b) {
  bf16x8 r;
  r[0] = (short)f2bf(a.x); r[1] = (short)f2bf(a.y);
  r[2] = (short)f2bf(a.z); r[3] = (short)f2bf(a.w);
  r[4] = (short)f2bf(b.x); r[5] = (short)f2bf(b.y);
  r[6] = (short)f2bf(b.z); r[7] = (short)f2bf(b.w);
  return r;
}
__device__ __forceinline__ void gload_lds16(const u16* g, u16* l) {
  __builtin_amdgcn_global_load_lds((__attribute__((address_space(1))) void*)g,
                                   (__attribute__((address_space(3))) void*)l, 16, 0, 0);
}

template <int CPR>
__device__ __forceinline__ int sw_off(int r, int c) {
  return (r * CPR + (c ^ (r & (CPR - 1)))) * 8;
}

// ---- fused prep: x->bf16 + Wo transpose + Wq/Wk/Wv transpose (hs=16 path) ----
__global__ __launch_bounds__(1024) void prep(
    const float* __restrict__ x, u16* __restrict__ xb,
    const float* __restrict__ Wq, const float* __restrict__ Wk,
    const float* __restrict__ Wv, const float* __restrict__ Wo,
    u16* __restrict__ WoT, u16* __restrict__ WT3) {
  const int bxg = blockIdx.x, by = blockIdx.y;
  if (bxg >= 128) {
    const int blk = (bxg - 128) * 32 + by;  // 0..511
    const int tid = threadIdx.y * 32 + threadIdx.x;
    const size_t i = ((size_t)blk * 1024 + tid) * 8;
    const float4 a = *(const float4*)&x[i];
    const float4 b2 = *(const float4*)&x[i + 4];
    *(bf16x8*)&xb[i] = pack8(a, b2);
    return;
  }
  __shared__ u16 t[32][33];
  const float* W;
  u16* T;
  int j0, wcol;
  if (bxg < 32) {
    j0 = bxg * 32; wcol = j0; W = Wo; T = WoT;
  } else {
    j0 = (bxg - 32) * 32;  // 0..3071
    const int g = j0 >> 10;
    W = (g == 0) ? Wq : (g == 1) ? Wk : Wv;
    T = WT3;
    wcol = j0 & 1023;
  }
  const int k0 = by * 32;
  t[threadIdx.y][threadIdx.x] =
      f2bf(W[(size_t)(k0 + threadIdx.y) * 1024 + wcol + threadIdx.x]);
  __syncthreads();
  T[(size_t)(j0 + threadIdx.y) * 1024 + k0 + threadIdx.x] = t[threadIdx.x][threadIdx.y];
}

// ---- fallback-path helpers (hs<16) ----
__global__ __launch_bounds__(256) void x_to_bf16(const float* __restrict__ x,
                                                 u16* __restrict__ xb) {
  const size_t i = ((size_t)blockIdx.x * 256 + threadIdx.x) * 8;
  const float4 a = *(const float4*)&x[i];
  const float4 b = *(const float4*)&x[i + 4];
  *(bf16x8*)&xb[i] = pack8(a, b);
}

__global__ void transpose_cols(const float* __restrict__ W0, const float* __restrict__ W1,
                               const float* __restrict__ W2, u16* __restrict__ T,
                               int h0, int hsx64) {
  __shared__ u16 t[32][33];
  const int j0 = blockIdx.x * 32;
  const int g = j0 / hsx64;
  const float* W = (g == 0) ? W0 : (g == 1) ? W1 : W2;
  const int wc0 = h0 * 64 + (j0 % hsx64);
  const int k0 = blockIdx.y * 32;
  t[threadIdx.y][threadIdx.x] =
      f2bf(W[(size_t)(k0 + threadIdx.y) * 1024 + wc0 + threadIdx.x]);
  __syncthreads();
  T[(size_t)(j0 + threadIdx.y) * 1024 + k0 + threadIdx.x] = t[threadIdx.x][threadIdx.y];
}

// ---- k2/k4: C = A[M][K] @ BT[N][K]^T, 128x128 tile, dbuf LDS (T3-min) ----
template <int MODE, int AF32>
__global__ __launch_bounds__(256, 2) void gemm_bt(
    const void* __restrict__ Av, const u16* __restrict__ BT,
    void* __restrict__ C0v, u16* __restrict__ C1, u16* __restrict__ C2,
    const float* __restrict__ bias, int M, int N, int K, int hs, int h0) {
  __shared__ __align__(16) u16 lsA[2][128 * 32];
  __shared__ __align__(16) u16 lsB[2][128 * 32];
  const int tid = threadIdx.x, lane = tid & 63, wv = tid >> 6;
  const int quad = lane >> 4, l16 = lane & 15;
  const int m0 = blockIdx.y * 128, n0 = blockIdx.x * 128;
  const int wm = (wv >> 1) * 64, wn = (wv & 1) * 64;
  const int hs64 = hs * 64;
  f32x4 acc[4][4] = {};

  if constexpr (!AF32) {
    // prologue: stage tile 0 -> buf 0
#pragma unroll
    for (int c = 0; c < 2; ++c) {
      const int P = c * 256 + tid, r = P >> 2;
      const int gcol = ((P & 3) ^ (r & 3)) * 8;
      gload_lds16((const u16*)Av + (size_t)(m0 + r) * K + gcol,
                  &lsA[0][(c * 256 + wv * 64) * 8]);
      gload_lds16(BT + (size_t)(n0 + r) * K + gcol,
                  &lsB[0][(c * 256 + wv * 64) * 8]);
    }
    __syncthreads();  // tile 0 landed
    const int nk = K >> 5;
    for (int kt = 0; kt < nk; ++kt) {
      const int buf = kt & 1;
      if (kt + 1 < nk) {  // issue DMA for tile kt+1 into buf^1 BEFORE compute
        const int k1 = (kt + 1) << 5;
#pragma unroll
        for (int c = 0; c < 2; ++c) {
          const int P = c * 256 + tid, r = P >> 2;
          const int gcol = ((P & 3) ^ (r & 3)) * 8;
          gload_lds16((const u16*)Av + (size_t)(m0 + r) * K + k1 + gcol,
                      &lsA[buf ^ 1][(c * 256 + wv * 64) * 8]);
          gload_lds16(BT + (size_t)(n0 + r) * K + k1 + gcol,
                      &lsB[buf ^ 1][(c * 256 + wv * 64) * 8]);
        }
      }
      bf16x8 af[4], bfr[4];
#pragma unroll
      for (int i = 0; i < 4; ++i)
        af[i] = *(const bf16x8*)&lsA[buf][sw_off<4>(wm + i * 16 + l16, quad)];
#pragma unroll
      for (int j = 0; j < 4; ++j)
        bfr[j] = *(const bf16x8*)&lsB[buf][sw_off<4>(wn + j * 16 + l16, quad)];
#pragma unroll
      for (int i = 0; i < 4; ++i)
#pragma unroll
        for (int j = 0; j < 4; ++j) acc[i][j] = MFMA_BF16(af[i], bfr[j], acc[i][j]);
      __syncthreads();  // drains vmcnt (tile kt+1 landed) + all reads of buf done
    }
  } else {
    // fallback reg-staged path (hs<16 only), single-buffered
    for (int k0 = 0; k0 < K; k0 += 32) {
      bf16x8 va[2], vb[2];
#pragma unroll
      for (int c = 0; c < 2; ++c) {
        const int P = c * 256 + tid, r = P >> 2, cc = P & 3;
        const float* Af = (const float*)Av;
        const float4 a0 = *(const float4*)&Af[(size_t)(m0 + r) * K + k0 + cc * 8];
        const float4 a1 = *(const float4*)&Af[(size_t)(m0 + r) * K + k0 + cc * 8 + 4];
        va[c] = pack8(a0, a1);
        vb[c] = *(const bf16x8*)&BT[(size_t)(n0 + r) * K + k0 + cc * 8];
      }
      __syncthreads();
#pragma unroll
      for (int c = 0; c < 2; ++c) {
        const int P = c * 256 + tid, r = P >> 2, cc = P & 3;
        *(bf16x8*)&lsA[0][sw_off<4>(r, cc)] = va[c];
        *(bf16x8*)&lsB[0][sw_off<4>(r, cc)] = vb[c];
      }
      __syncthreads();
      bf16x8 af[4], bfr[4];
#pragma unroll
      for (int i = 0; i < 4; ++i)
        af[i] = *(const bf16x8*)&lsA[0][sw_off<4>(wm + i * 16 + l16, quad)];
#pragma unroll
      for (int j = 0; j < 4; ++j)
        bfr[j] = *(const bf16x8*)&lsB[0][sw_off<4>(wn + j * 16 + l16, quad)];
#pragma unroll
      for (int i = 0; i < 4; ++i)
#pragma unroll
        for (int j = 0; j < 4; ++j) acc[i][j] = MFMA_BF16(af[i], bfr[j], acc[i][j]);
    }
  }

  if constexpr (MODE == 3) {
#pragma unroll
    for (int j = 0; j < 4; ++j) {
      const int n = n0 + wn + j * 16 + l16;  // region constant over i,r
#pragma unroll
      for (int i = 0; i < 4; ++i) {
        const int mb = m0 + wm + i * 16 + quad * 4;  // 4-aligned, no 2048-cross
        const int b = mb >> 11, s0 = mb & 2047;
        if (n < hs64) {
#pragma unroll
          for (int r = 0; r < 4; ++r)
            ((u16*)C0v)[((size_t)b * 2048 + s0 + r) * hs64 + n] =
                f2bf(acc[i][j][r] * QSCALE);
        } else if (n < 2 * hs64) {
#pragma unroll
          for (int r = 0; r < 4; ++r)
            C1[((size_t)b * 2048 + s0 + r) * hs64 + (n - hs64)] = f2bf(acc[i][j][r]);
        } else {
          const int nn = n - 2 * hs64;  // V: r-adjacent = s-consecutive -> pack 8B
          uint2 o;
          o.x = (unsigned)f2bf(acc[i][j][0]) | ((unsigned)f2bf(acc[i][j][1]) << 16);
          o.y = (unsigned)f2bf(acc[i][j][2]) | ((unsigned)f2bf(acc[i][j][3]) << 16);
          *(uint2*)&C2[((size_t)(b * hs + (nn >> 6)) * 64 + (nn & 63)) * 2048 + s0] = o;
        }
      }
    }
  } else {
#pragma unroll
    for (int i = 0; i < 4; ++i)
#pragma unroll
      for (int j = 0; j < 4; ++j) {
        const int n = n0 + wn + j * 16 + l16;
        float bv = 0.f;
        if constexpr (MODE == 1) bv = bias[n];
#pragma unroll
        for (int r = 0; r < 4; ++r) {
          const int m = m0 + wm + i * 16 + quad * 4 + r;
          const int b = (m >= hs * 128) ? 1 : 0;
          const int rp = m - b * hs * 128;
          ((float*)C0v)[(size_t)(b * 2048 + h0 * 128 + rp) * 1024 + n] =
              acc[i][j][r] + bv;
        }
      }
  }
}

// ---- k3: attn v11 (unchanged from r6) ----
__global__ __launch_bounds__(256, 2) void attn_fwd(
    const u16* __restrict__ Qsl, const u16* __restrict__ Ksl,
    const u16* __restrict__ VTsl, u16* __restrict__ A2sl, int hs) {
  __shared__ __align__(16) u16 lsK[2][64 * 64];  // dead after kt loop -> O scratch
  __shared__ __align__(16) u16 lsV[2][64 * 64];
  __shared__ __align__(16) u16 lsP[4][16 * 64];
  __shared__ __align__(16) float scrl[64];
  const int tid = threadIdx.x, lane = tid & 63, wv = tid >> 6;
  const int quad = lane >> 4, l16 = lane & 15;
  const int grp = wv >> 1, wq = wv & 1;

  // bijective XCD-chunk swizzle (gridDim.x % 8 == 0)
  const int cpx = gridDim.x >> 3;
  const int w = (blockIdx.x & 7) * cpx + (blockIdx.x >> 3);
  const int bh = w >> 4, bx = w & 15;

  const int b = (bh >= hs) ? 1 : 0, hh = bh - b * hs;
  const int hs64 = hs * 64;
  const u16* Qb = Qsl + (size_t)b * 2048 * hs64;
  const u16* Kb = Ksl + (size_t)b * 2048 * hs64;
  const u16* Vb = VTsl + (size_t)(b * hs + hh) * 64 * 2048;
  u16* A2b = A2sl + (size_t)(b * hs + hh) * 2048 * 64;
  u16* lsPw = &lsP[wv][0];
  float* scro = (float*)&lsK[0][0];

  bf16x8 ones;
#pragma unroll
  for (int i = 0; i < 8; ++i) ones[i] = (short)0x3F80;

  const int prow = l16 >> 1;       // lsP row sub-index / XOR mask
  const int pb0 = (l16 & 1) << 2;  // q&1 selects 32-u16 half of the 128B row

  // constant per-thread staging geometry
  const int Pa = tid, ra = Pa >> 3, ca = (Pa & 7) ^ (ra & 7);
  const int Pb2 = 256 + tid, rb = Pb2 >> 3, cb = (Pb2 & 7) ^ (rb & 7);
  const size_t kTileStep = (size_t)64 * hs64;
  const u16* const kBa = Kb + (size_t)ra * hs64 + hh * 64 + ca * 8;
  const u16* const kBb = Kb + (size_t)rb * hs64 + hh * 64 + cb * 8;
  const u16* const vBa = Vb + (size_t)ra * 2048 + ca * 8;
  const u16* const vBb = Vb + (size_t)rb * 2048 + cb * 8;
  const int dA = (wv * 64) * 8;
  const int dB = (256 + wv * 64) * 8;

  for (int half = 0; half < 2; ++half) {
    const int qt = (half == 0) ? bx : 31 - bx;
    const int q0 = qt * 64;

    bf16x8 qf[2][2];
#pragma unroll
    for (int j = 0; j < 2; ++j)
#pragma unroll
      for (int ks = 0; ks < 2; ++ks)
        qf[j][ks] = *(const bf16x8*)&Qb[(size_t)(q0 + wq * 32 + j * 16 + l16) * hs64 +
                                        hh * 64 + ks * 32 + quad * 8];

    f32x4 acc_o[2][4] = {};
    f32x4 acc_l[2] = {};

    const u16* pkA = kBa;
    const u16* pkB = kBb;
    const u16* pvA = vBa;
    const u16* pvB = vBb;

    __syncthreads();  // prev half fully consumed before tile-0 DMA
    gload_lds16(pkA, &lsK[0][dA]);
    gload_lds16(pkB, &lsK[0][dB]);
    gload_lds16(pvA, &lsV[0][dA]);
    gload_lds16(pvB, &lsV[0][dB]);

    auto body = [&](int buf, bool domask) {
      f32x4 accs[2][2] = {};  // [j][nj]
#pragma unroll
      for (int ks = 0; ks < 2; ++ks)
#pragma unroll
        for (int nj = 0; nj < 2; ++nj) {
          const bf16x8 kf = *(const bf16x8*)
              &lsK[buf][sw_off<8>(grp * 32 + nj * 16 + l16, ks * 4 + quad)];
          accs[0][nj] = MFMA_BF16(kf, qf[0][ks], accs[0][nj]);
          accs[1][nj] = MFMA_BF16(kf, qf[1][ks], accs[1][nj]);
        }
#pragma unroll
      for (int j = 0; j < 2; ++j) {
        const int grow = wq * 32 + j * 16 + l16;
#pragma unroll
        for (int nj = 0; nj < 2; ++nj) {
#pragma unroll
          for (int r = 0; r < 4; ++r) {
            float p = exp2f(accs[j][nj][r]);
            if (domask) {
              const int keyb = grp * 32 + nj * 16 + quad * 4;
              p = (keyb + r > grow) ? 0.f : p;
            }
            accs[j][nj][r] = p;
          }
          union { float f; unsigned int u; } t0, t1, t2, t3;
          t0.f = accs[j][nj][0]; t1.f = accs[j][nj][1];
          t2.f = accs[j][nj][2]; t3.f = accs[j][nj][3];
          uint2 wpk;
          wpk.x = (t0.u >> 16) | (t1.u & 0xFFFF0000u);
          wpk.y = (t2.u >> 16) | (t3.u & 0xFFFF0000u);
          const int row = j * 8 + prow;
          const int chunk = (pb0 + 2 * nj + (quad >> 1)) ^ prow;
          *(uint2*)&lsPw[row * 64 + chunk * 8 + (quad & 1) * 4] = wpk;
        }
      }
      bf16x8 pf[2];
#pragma unroll
      for (int j = 0; j < 2; ++j) {
        const int row = j * 8 + prow;
        const int chunk = (pb0 + quad) ^ prow;
        pf[j] = *(const bf16x8*)&lsPw[row * 64 + chunk * 8];
        acc_l[j] = MFMA_BF16(ones, pf[j], acc_l[j]);
      }
#pragma unroll
      for (int njo = 0; njo < 4; ++njo) {
        const bf16x8 vf = *(const bf16x8*)
            &lsV[buf][sw_off<8>(njo * 16 + l16, grp * 4 + quad)];
        acc_o[0][njo] = MFMA_BF16(vf, pf[0], acc_o[0][njo]);
        acc_o[1][njo] = MFMA_BF16(vf, pf[1], acc_o[1][njo]);
      }
    };

    for (int kt = 0; kt < qt; ++kt) {  // off-diagonal: mask-free hot body
      const int buf = kt & 1, nb = buf ^ 1;
      __syncthreads();  // drains DMA of tile kt; buf^1 free
      pkA += kTileStep; pkB += kTileStep; pvA += 64; pvB += 64;
      gload_lds16(pkA, &lsK[nb][dA]);
      gload_lds16(pkB, &lsK[nb][dB]);
      gload_lds16(pvA, &lsV[nb][dA]);
      gload_lds16(pvB, &lsV[nb][dB]);
      body(buf, false);
    }
    {  // peeled diagonal tile kt == qt (no prefetch, masked)
      __syncthreads();
      body(qt & 1, true);
    }

    // combine: exact partial sums (no-max softmax needs no rescale)
    __syncthreads();
    if (grp == 1) {
#pragma unroll
      for (int j = 0; j < 2; ++j) {
#pragma unroll
        for (int njo = 0; njo < 4; ++njo) {
          const int ch = (njo * 4 + quad) ^ l16;
          *(f32x4*)&scro[(size_t)(wq * 32 + j * 16 + l16) * 64 + ch * 4] =
              acc_o[j][njo];
        }
        if (quad == 0) scrl[wq * 32 + j * 16 + l16] = acc_l[j][0];
      }
    }
    __syncthreads();
    if (grp == 0) {
#pragma unroll
      for (int j = 0; j < 2; ++j) {
        const int ql = wq * 32 + j * 16 + l16;
        const float inv = 1.0f / (acc_l[j][0] + scrl[ql]);
#pragma unroll
        for (int njo = 0; njo < 4; ++njo) {
          const int ch = (njo * 4 + quad) ^ l16;
          const f32x4 ob = *(const f32x4*)&scro[(size_t)ql * 64 + ch * 4];
          uint2 o;
          o.x = (unsigned)f2bf((acc_o[j][njo][0] + ob[0]) * inv) |
                ((unsigned)f2bf((acc_o[j][njo][1] + ob[1]) * inv) << 16);
          o.y = (unsigned)f2bf((acc_o[j][njo][2] + ob[2]) * inv) |
                ((unsigned)f2bf((acc_o[j][njo][3] + ob[3]) * inv) << 16);
          *(uint2*)&A2b[(size_t)(q0 + ql) * 64 + njo * 16 + quad * 4] = o;
        }
      }
    }
  }
}

// ---------------- launcher ----------------
extern "C" void kernel_launch(void* const* d_in, const int* in_sizes, int n_in,
                              void* d_out, int out_size, void* d_ws, size_t ws_size,
                              hipStream_t stream) {
  (void)in_sizes; (void)n_in; (void)out_size;
  const float* x  = (const float*)d_in[0];
  const float* Wq = (const float*)d_in[1];
  const float* Wk = (const float*)d_in[2];
  const float* Wv = (const float*)d_in[3];
  const float* Wo = (const float*)d_in[4];
  const float* bo = (const float*)d_in[5];
  float* out = (float*)d_out;
  char* ws = (char*)d_ws;
  const size_t MB = 1024 * 1024;
  const size_t KB = 1024;

  int hs = 2;
  if      (ws_size >= 2 * MB + 16 * 2432 * KB) hs = 16;
  else if (ws_size >= 2 * MB +  8 * 2432 * KB) hs = 8;
  else if (ws_size >= 2 * MB +  4 * 2432 * KB) hs = 4;

  u16* WoT   = (u16*)(ws);
  u16* Ksl   = (u16*)(ws + 2 * MB);
  u16* VTsl  = (u16*)(ws + 2 * MB + (size_t)hs *  512 * KB);
  u16* A2sl  = (u16*)(ws + 2 * MB + (size_t)hs * 1024 * KB);
  u16* WT3sl = (u16*)(ws + 2 * MB + (size_t)hs * 1536 * KB);
  u16* Qsl   = (u16*)(ws + 2 * MB + (size_t)hs * 1920 * KB);

  if (hs == 16) {
    u16* xb = A2sl;  // aliases A2sl: consumed by k2, overwritten by k3
    prep<<<dim3(144, 32), dim3(32, 32), 0, stream>>>(x, xb, Wq, Wk, Wv, Wo, WoT, WT3sl);
    gemm_bt<3, 0><<<dim3(24, 32), 256, 0, stream>>>(
        (const void*)xb, WT3sl, (void*)Qsl, Ksl, VTsl, nullptr, 4096, 3072, 1024, 16, 0);
    attn_fwd<<<dim3(512), 256, 0, stream>>>(Qsl, Ksl, VTsl, A2sl, 16);
    gemm_bt<1, 0><<<dim3(8, 32), 256, 0, stream>>>(
        (const void*)A2sl, WoT, (void*)out, nullptr, nullptr, bo, 4096, 1024, 1024, 16, 0);
  } else {
    transpose_cols<<<dim3(32, 32), dim3(32, 32), 0, stream>>>(Wo, Wo, Wo, WoT, 0, 1024);
    for (int h0 = 0; h0 < 16; h0 += hs) {
      transpose_cols<<<dim3(6 * hs, 32), dim3(32, 32), 0, stream>>>(Wq, Wk, Wv, WT3sl, h0, hs * 64);
      gemm_bt<3, 1><<<dim3((3 * hs) / 2, 32), 256, 0, stream>>>(
          (const void*)x, WT3sl, (void*)Qsl, Ksl, VTsl, nullptr, 4096, 3 * hs * 64, 1024, hs, h0);
      attn_fwd<<<dim3(16 * 2 * hs), 256, 0, stream>>>(Qsl, Ksl, VTsl, A2sl, hs);
      gemm_bt<1, 0><<<dim3(8, 2 * hs), 256, 0, stream>>>(
          (const void*)A2sl, WoT, (void*)out, nullptr, nullptr, bo, 2 * hs * 128, 1024, 1024, hs, h0);
    }
  }
}

// Round 8
// 179.525 us; speedup vs baseline: 1.1132x; 1.0314x over previous
//
#include <hip/hip_runtime.h>
#include <stdint.h>

// MHA forward.  Inputs FP32, output FP32.  Compute: bf16 MFMA, fp32 accumulate.
// B=2,S=2048,D=1024,H=16,HD=64.
//
// hs=16 fast path (4 launches; ~80us of wall is harness-fixed overhead):
//   prep: x fp32->bf16 + Wo transpose + Wq/Wk/Wv col transpose (one kernel)
//   k2  : xb @ WT3sl^T -> Qsl (pre-scaled 0.125*log2e) / Ksl, VTsl
//         [dbuf global_load_lds, r7]
//   k3  : attn v12 (this round).  v11 was chain-bound: per iter the wave runs
//         kf-read -> QK MFMA -> exp2/pack -> lsP roundtrip -> PV MFMA strictly
//         serially; pipe busies (DS40+VALU40+MFMA16) sum to ~96% with nothing
//         saturated.  v12 pipelines across k-tiles: S(kt) held in regs, iter kt
//         computes QK(kt+1) [MFMA/DS] || softmax(kt) [VALU] || PV(kt) [MFMA/DS];
//         3-buffer K/V rotation (bc=kt, bn=kt+1, DMA kt+2 -> bf), ONE barrier
//         per iter.  S ping-pong via static lambda roles (no runtime reg-array
//         indexing).  exp2 via __builtin_amdgcn_exp2f (bare v_exp_f32).
//   k4  : A2sl @ WoT^T + bo -> fp32 out  [dbuf global_load_lds]

typedef unsigned short u16;
typedef __attribute__((ext_vector_type(8))) short bf16x8;
typedef __attribute__((ext_vector_type(4))) float f32x4;

#define MFMA_BF16(a, b, c) __builtin_amdgcn_mfma_f32_16x16x32_bf16((a), (b), (c), 0, 0, 0)
#define QSCALE 0.18033688011112042f  // 0.125 * log2(e)

#if __has_builtin(__builtin_amdgcn_exp2f)
#define EXP2(x) __builtin_amdgcn_exp2f(x)
#else
#define EXP2(x) exp2f(x)
#endif

__device__ __forceinline__ u16 f2bf(float f) {  // RNE
  union { float f; unsigned int u; } x; x.f = f;
  unsigned int r = x.u + 0x7fffu + ((x.u >> 16) & 1u);
  return (u16)(r >> 16);
}
__device__ __forceinline__ bf16x8 pack8(float4 a, float4 b) {
  bf16x8 r;
  r[0] = (short)f2bf(a.x); r[1] = (short)f2bf(a.y);
  r[2] = (short)f2bf(a.z); r[3] = (short)f2bf(a.w);
  r[4] = (short)f2bf(b.x); r[5] = (short)f2bf(b.y);
  r[6] = (short)f2bf(b.z); r[7] = (short)f2bf(b.w);
  return r;
}
__device__ __forceinline__ void gload_lds16(const u16* g, u16* l) {
  __builtin_amdgcn_global_load_lds((__attribute__((address_space(1))) void*)g,
                                   (__attribute__((address_space(3))) void*)l, 16, 0, 0);
}

template <int CPR>
__device__ __forceinline__ int sw_off(int r, int c) {
  return (r * CPR + (c ^ (r & (CPR - 1)))) * 8;
}

// ---- fused prep: x->bf16 + Wo transpose + Wq/Wk/Wv transpose (hs=16 path) ----
__global__ __launch_bounds__(1024) void prep(
    const float* __restrict__ x, u16* __restrict__ xb,
    const float* __restrict__ Wq, const float* __restrict__ Wk,
    const float* __restrict__ Wv, const float* __restrict__ Wo,
    u16* __restrict__ WoT, u16* __restrict__ WT3) {
  const int bxg = blockIdx.x, by = blockIdx.y;
  if (bxg >= 128) {
    const int blk = (bxg - 128) * 32 + by;  // 0..511
    const int tid = threadIdx.y * 32 + threadIdx.x;
    const size_t i = ((size_t)blk * 1024 + tid) * 8;
    const float4 a = *(const float4*)&x[i];
    const float4 b2 = *(const float4*)&x[i + 4];
    *(bf16x8*)&xb[i] = pack8(a, b2);
    return;
  }
  __shared__ u16 t[32][33];
  const float* W;
  u16* T;
  int j0, wcol;
  if (bxg < 32) {
    j0 = bxg * 32; wcol = j0; W = Wo; T = WoT;
  } else {
    j0 = (bxg - 32) * 32;  // 0..3071
    const int g = j0 >> 10;
    W = (g == 0) ? Wq : (g == 1) ? Wk : Wv;
    T = WT3;
    wcol = j0 & 1023;
  }
  const int k0 = by * 32;
  t[threadIdx.y][threadIdx.x] =
      f2bf(W[(size_t)(k0 + threadIdx.y) * 1024 + wcol + threadIdx.x]);
  __syncthreads();
  T[(size_t)(j0 + threadIdx.y) * 1024 + k0 + threadIdx.x] = t[threadIdx.x][threadIdx.y];
}

// ---- fallback-path helpers (hs<16) ----
__global__ __launch_bounds__(256) void x_to_bf16(const float* __restrict__ x,
                                                 u16* __restrict__ xb) {
  const size_t i = ((size_t)blockIdx.x * 256 + threadIdx.x) * 8;
  const float4 a = *(const float4*)&x[i];
  const float4 b = *(const float4*)&x[i + 4];
  *(bf16x8*)&xb[i] = pack8(a, b);
}

__global__ void transpose_cols(const float* __restrict__ W0, const float* __restrict__ W1,
                               const float* __restrict__ W2, u16* __restrict__ T,
                               int h0, int hsx64) {
  __shared__ u16 t[32][33];
  const int j0 = blockIdx.x * 32;
  const int g = j0 / hsx64;
  const float* W = (g == 0) ? W0 : (g == 1) ? W1 : W2;
  const int wc0 = h0 * 64 + (j0 % hsx64);
  const int k0 = blockIdx.y * 32;
  t[threadIdx.y][threadIdx.x] =
      f2bf(W[(size_t)(k0 + threadIdx.y) * 1024 + wc0 + threadIdx.x]);
  __syncthreads();
  T[(size_t)(j0 + threadIdx.y) * 1024 + k0 + threadIdx.x] = t[threadIdx.x][threadIdx.y];
}

// ---- k2/k4: C = A[M][K] @ BT[N][K]^T, 128x128 tile, dbuf LDS (T3-min) ----
template <int MODE, int AF32>
__global__ __launch_bounds__(256, 2) void gemm_bt(
    const void* __restrict__ Av, const u16* __restrict__ BT,
    void* __restrict__ C0v, u16* __restrict__ C1, u16* __restrict__ C2,
    const float* __restrict__ bias, int M, int N, int K, int hs, int h0) {
  __shared__ __align__(16) u16 lsA[2][128 * 32];
  __shared__ __align__(16) u16 lsB[2][128 * 32];
  const int tid = threadIdx.x, lane = tid & 63, wv = tid >> 6;
  const int quad = lane >> 4, l16 = lane & 15;
  const int m0 = blockIdx.y * 128, n0 = blockIdx.x * 128;
  const int wm = (wv >> 1) * 64, wn = (wv & 1) * 64;
  const int hs64 = hs * 64;
  f32x4 acc[4][4] = {};

  if constexpr (!AF32) {
    // prologue: stage tile 0 -> buf 0
#pragma unroll
    for (int c = 0; c < 2; ++c) {
      const int P = c * 256 + tid, r = P >> 2;
      const int gcol = ((P & 3) ^ (r & 3)) * 8;
      gload_lds16((const u16*)Av + (size_t)(m0 + r) * K + gcol,
                  &lsA[0][(c * 256 + wv * 64) * 8]);
      gload_lds16(BT + (size_t)(n0 + r) * K + gcol,
                  &lsB[0][(c * 256 + wv * 64) * 8]);
    }
    __syncthreads();  // tile 0 landed
    const int nk = K >> 5;
    for (int kt = 0; kt < nk; ++kt) {
      const int buf = kt & 1;
      if (kt + 1 < nk) {  // issue DMA for tile kt+1 into buf^1 BEFORE compute
        const int k1 = (kt + 1) << 5;
#pragma unroll
        for (int c = 0; c < 2; ++c) {
          const int P = c * 256 + tid, r = P >> 2;
          const int gcol = ((P & 3) ^ (r & 3)) * 8;
          gload_lds16((const u16*)Av + (size_t)(m0 + r) * K + k1 + gcol,
                      &lsA[buf ^ 1][(c * 256 + wv * 64) * 8]);
          gload_lds16(BT + (size_t)(n0 + r) * K + k1 + gcol,
                      &lsB[buf ^ 1][(c * 256 + wv * 64) * 8]);
        }
      }
      bf16x8 af[4], bfr[4];
#pragma unroll
      for (int i = 0; i < 4; ++i)
        af[i] = *(const bf16x8*)&lsA[buf][sw_off<4>(wm + i * 16 + l16, quad)];
#pragma unroll
      for (int j = 0; j < 4; ++j)
        bfr[j] = *(const bf16x8*)&lsB[buf][sw_off<4>(wn + j * 16 + l16, quad)];
#pragma unroll
      for (int i = 0; i < 4; ++i)
#pragma unroll
        for (int j = 0; j < 4; ++j) acc[i][j] = MFMA_BF16(af[i], bfr[j], acc[i][j]);
      __syncthreads();  // drains vmcnt (tile kt+1 landed) + all reads of buf done
    }
  } else {
    // fallback reg-staged path (hs<16 only), single-buffered
    for (int k0 = 0; k0 < K; k0 += 32) {
      bf16x8 va[2], vb[2];
#pragma unroll
      for (int c = 0; c < 2; ++c) {
        const int P = c * 256 + tid, r = P >> 2, cc = P & 3;
        const float* Af = (const float*)Av;
        const float4 a0 = *(const float4*)&Af[(size_t)(m0 + r) * K + k0 + cc * 8];
        const float4 a1 = *(const float4*)&Af[(size_t)(m0 + r) * K + k0 + cc * 8 + 4];
        va[c] = pack8(a0, a1);
        vb[c] = *(const bf16x8*)&BT[(size_t)(n0 + r) * K + k0 + cc * 8];
      }
      __syncthreads();
#pragma unroll
      for (int c = 0; c < 2; ++c) {
        const int P = c * 256 + tid, r = P >> 2, cc = P & 3;
        *(bf16x8*)&lsA[0][sw_off<4>(r, cc)] = va[c];
        *(bf16x8*)&lsB[0][sw_off<4>(r, cc)] = vb[c];
      }
      __syncthreads();
      bf16x8 af[4], bfr[4];
#pragma unroll
      for (int i = 0; i < 4; ++i)
        af[i] = *(const bf16x8*)&lsA[0][sw_off<4>(wm + i * 16 + l16, quad)];
#pragma unroll
      for (int j = 0; j < 4; ++j)
        bfr[j] = *(const bf16x8*)&lsB[0][sw_off<4>(wn + j * 16 + l16, quad)];
#pragma unroll
      for (int i = 0; i < 4; ++i)
#pragma unroll
        for (int j = 0; j < 4; ++j) acc[i][j] = MFMA_BF16(af[i], bfr[j], acc[i][j]);
    }
  }

  if constexpr (MODE == 3) {
#pragma unroll
    for (int j = 0; j < 4; ++j) {
      const int n = n0 + wn + j * 16 + l16;  // region constant over i,r
#pragma unroll
      for (int i = 0; i < 4; ++i) {
        const int mb = m0 + wm + i * 16 + quad * 4;  // 4-aligned, no 2048-cross
        const int b = mb >> 11, s0 = mb & 2047;
        if (n < hs64) {
#pragma unroll
          for (int r = 0; r < 4; ++r)
            ((u16*)C0v)[((size_t)b * 2048 + s0 + r) * hs64 + n] =
                f2bf(acc[i][j][r] * QSCALE);
        } else if (n < 2 * hs64) {
#pragma unroll
          for (int r = 0; r < 4; ++r)
            C1[((size_t)b * 2048 + s0 + r) * hs64 + (n - hs64)] = f2bf(acc[i][j][r]);
        } else {
          const int nn = n - 2 * hs64;  // V: r-adjacent = s-consecutive -> pack 8B
          uint2 o;
          o.x = (unsigned)f2bf(acc[i][j][0]) | ((unsigned)f2bf(acc[i][j][1]) << 16);
          o.y = (unsigned)f2bf(acc[i][j][2]) | ((unsigned)f2bf(acc[i][j][3]) << 16);
          *(uint2*)&C2[((size_t)(b * hs + (nn >> 6)) * 64 + (nn & 63)) * 2048 + s0] = o;
        }
      }
    }
  } else {
#pragma unroll
    for (int i = 0; i < 4; ++i)
#pragma unroll
      for (int j = 0; j < 4; ++j) {
        const int n = n0 + wn + j * 16 + l16;
        float bv = 0.f;
        if constexpr (MODE == 1) bv = bias[n];
#pragma unroll
        for (int r = 0; r < 4; ++r) {
          const int m = m0 + wm + i * 16 + quad * 4 + r;
          const int b = (m >= hs * 128) ? 1 : 0;
          const int rp = m - b * hs * 128;
          ((float*)C0v)[(size_t)(b * 2048 + h0 * 128 + rp) * 1024 + n] =
              acc[i][j][r] + bv;
        }
      }
  }
}

// ---- k3: attn v12 (pipelined) ----
// 256 thr / 4 waves.  wq = wv&1 (32 q-rows), grp = wv>>1 (32-key half).
// Per iter kt: QK(kt+1) from bn || softmax S(kt) || PV(kt) from bc; DMA kt+2
// into bf; ONE barrier/iter (drains DMA kt+1; gates bf overwrite).  3-buffer
// K/V rotation; S held in regs across iters (ping-pong sA/sB, static roles).
// Tail = masked softmax + PV of the diagonal tile.  Combine: grp B writes
// partial O (f32) + l into dead lsK[0..1]; grp A adds (exact sum), stores.
__global__ __launch_bounds__(256, 2) void attn_fwd(
    const u16* __restrict__ Qsl, const u16* __restrict__ Ksl,
    const u16* __restrict__ VTsl, u16* __restrict__ A2sl, int hs) {
  __shared__ __align__(16) u16 lsK[3][64 * 64];  // [key][hd] CPR=8; [0..1] dead
                                                 // after kt loop -> f32 O scratch
  __shared__ __align__(16) u16 lsV[3][64 * 64];  // [hd][key] CPR=8
  __shared__ __align__(16) u16 lsP[4][16 * 64];  // per-wave P^T, 128B rows, XOR-swz
  __shared__ __align__(16) float scrl[64];
  const int tid = threadIdx.x, lane = tid & 63, wv = tid >> 6;
  const int quad = lane >> 4, l16 = lane & 15;
  const int grp = wv >> 1, wq = wv & 1;

  // bijective XCD-chunk swizzle (gridDim.x % 8 == 0)
  const int cpx = gridDim.x >> 3;
  const int w = (blockIdx.x & 7) * cpx + (blockIdx.x >> 3);
  const int bh = w >> 4, bx = w & 15;

  const int b = (bh >= hs) ? 1 : 0, hh = bh - b * hs;
  const int hs64 = hs * 64;
  const u16* Qb = Qsl + (size_t)b * 2048 * hs64;
  const u16* Kb = Ksl + (size_t)b * 2048 * hs64;
  const u16* Vb = VTsl + (size_t)(b * hs + hh) * 64 * 2048;
  u16* A2b = A2sl + (size_t)(b * hs + hh) * 2048 * 64;
  u16* lsPw = &lsP[wv][0];
  float* scro = (float*)&lsK[0][0];  // 16KB spans lsK[0..1]

  bf16x8 ones;
#pragma unroll
  for (int i = 0; i < 8; ++i) ones[i] = (short)0x3F80;

  const int prow = l16 >> 1;       // lsP row sub-index / XOR mask
  const int pb0 = (l16 & 1) << 2;  // q&1 selects 32-u16 half of the 128B row

  // constant per-thread staging geometry
  const int Pa = tid, ra = Pa >> 3, ca = (Pa & 7) ^ (ra & 7);
  const int Pb2 = 256 + tid, rb = Pb2 >> 3, cb = (Pb2 & 7) ^ (rb & 7);
  const size_t kTileStep = (size_t)64 * hs64;
  const u16* const kBa = Kb + (size_t)ra * hs64 + hh * 64 + ca * 8;
  const u16* const kBb = Kb + (size_t)rb * hs64 + hh * 64 + cb * 8;
  const u16* const vBa = Vb + (size_t)ra * 2048 + ca * 8;
  const u16* const vBb = Vb + (size_t)rb * 2048 + cb * 8;
  const int dA = (wv * 64) * 8;
  const int dB = (256 + wv * 64) * 8;

  for (int half = 0; half < 2; ++half) {
    const int qt = (half == 0) ? bx : 31 - bx;
    const int q0 = qt * 64;

    bf16x8 qf[2][2];
#pragma unroll
    for (int j = 0; j < 2; ++j)
#pragma unroll
      for (int ks = 0; ks < 2; ++ks)
        qf[j][ks] = *(const bf16x8*)&Qb[(size_t)(q0 + wq * 32 + j * 16 + l16) * hs64 +
                                        hh * 64 + ks * 32 + quad * 8];

    f32x4 acc_o[2][4] = {};
    f32x4 acc_l[2] = {};

    const u16* pkA = kBa;
    const u16* pkB = kBb;
    const u16* pvA = vBa;
    const u16* pvB = vBb;
    int bc = 0, bn = 1, bf_ = 2;

    auto stage = [&](int bs) {  // DMA one K/V tile, advance source pointers
      gload_lds16(pkA, &lsK[bs][dA]);
      gload_lds16(pkB, &lsK[bs][dB]);
      gload_lds16(pvA, &lsV[bs][dA]);
      gload_lds16(pvB, &lsV[bs][dB]);
      pkA += kTileStep; pkB += kTileStep; pvA += 64; pvB += 64;
    };
    auto qk = [&](int bK, f32x4 (&S)[2][2]) {  // S^T = K Q^T
#pragma unroll
      for (int j = 0; j < 2; ++j)
#pragma unroll
        for (int nj = 0; nj < 2; ++nj) S[j][nj] = f32x4{0.f, 0.f, 0.f, 0.f};
#pragma unroll
      for (int ks = 0; ks < 2; ++ks)
#pragma unroll
        for (int nj = 0; nj < 2; ++nj) {
          const bf16x8 kf = *(const bf16x8*)
              &lsK[bK][sw_off<8>(grp * 32 + nj * 16 + l16, ks * 4 + quad)];
          S[0][nj] = MFMA_BF16(kf, qf[0][ks], S[0][nj]);
          S[1][nj] = MFMA_BF16(kf, qf[1][ks], S[1][nj]);
        }
    };
    auto smpv = [&](f32x4 (&S)[2][2], int bV, bool domask) {  // softmax + PV + l
#pragma unroll
      for (int j = 0; j < 2; ++j) {
        const int grow = wq * 32 + j * 16 + l16;
#pragma unroll
        for (int nj = 0; nj < 2; ++nj) {
#pragma unroll
          for (int r = 0; r < 4; ++r) {
            float p = EXP2(S[j][nj][r]);
            if (domask) {
              const int keyb = grp * 32 + nj * 16 + quad * 4;
              p = (keyb + r > grow) ? 0.f : p;
            }
            S[j][nj][r] = p;
          }
          union { float f; unsigned int u; } t0, t1, t2, t3;
          t0.f = S[j][nj][0]; t1.f = S[j][nj][1];
          t2.f = S[j][nj][2]; t3.f = S[j][nj][3];
          uint2 wpk;
          wpk.x = (t0.u >> 16) | (t1.u & 0xFFFF0000u);
          wpk.y = (t2.u >> 16) | (t3.u & 0xFFFF0000u);
          const int row = j * 8 + prow;
          const int chunk = (pb0 + 2 * nj + (quad >> 1)) ^ prow;
          *(uint2*)&lsPw[row * 64 + chunk * 8 + (quad & 1) * 4] = wpk;
        }
      }
      bf16x8 pf[2];
#pragma unroll
      for (int j = 0; j < 2; ++j) {
        const int row = j * 8 + prow;
        const int chunk = (pb0 + quad) ^ prow;
        pf[j] = *(const bf16x8*)&lsPw[row * 64 + chunk * 8];
        acc_l[j] = MFMA_BF16(ones, pf[j], acc_l[j]);
      }
#pragma unroll
      for (int njo = 0; njo < 4; ++njo) {
        const bf16x8 vf = *(const bf16x8*)
            &lsV[bV][sw_off<8>(njo * 16 + l16, grp * 4 + quad)];
        acc_o[0][njo] = MFMA_BF16(vf, pf[0], acc_o[0][njo]);
        acc_o[1][njo] = MFMA_BF16(vf, pf[1], acc_o[1][njo]);
      }
    };
    // one pipelined iteration: Sc = S(kt) ready; computes S(kt+1) into Sn
    auto step = [&](f32x4 (&Sc)[2][2], f32x4 (&Sn)[2][2], int kt) {
      __syncthreads();                 // DMA(kt+1) landed in bn; bf_ reads done
      if (kt + 2 <= qt) stage(bf_);    // DMA(kt+2) -> bf_, in flight this iter
      qk(bn, Sn);                      // QK(kt+1): DS+MFMA
      smpv(Sc, bc, false);             // softmax(kt): VALU (indep) + PV(kt)
      const int t = bc; bc = bn; bn = bf_; bf_ = t;
    };

    __syncthreads();   // prev half fully consumed (incl. scro region)
    stage(0);          // tile 0 -> buf 0
    __syncthreads();   // tile 0 landed
    if (qt >= 1) stage(1);  // tile 1 -> buf 1, in flight under QK(0)

    f32x4 sA[2][2], sB[2][2];
    qk(0, sA);  // S(0)

    int kt = 0;
    while (kt + 1 < qt) { step(sA, sB, kt); step(sB, sA, kt + 1); kt += 2; }
    bool curA = true;
    if (kt < qt) { step(sA, sB, kt); curA = false; }
    // tail: diagonal tile qt (masked); V(qt) is in bc after rotation
    if (curA) smpv(sA, bc, true); else smpv(sB, bc, true);

    // combine: exact partial sums (no-max softmax needs no rescale)
    __syncthreads();  // all lsK/lsV reads done -> scro region free
    if (grp == 1) {
#pragma unroll
      for (int j = 0; j < 2; ++j) {
#pragma unroll
        for (int njo = 0; njo < 4; ++njo) {
          const int ch = (njo * 4 + quad) ^ l16;
          *(f32x4*)&scro[(size_t)(wq * 32 + j * 16 + l16) * 64 + ch * 4] =
              acc_o[j][njo];
        }
        if (quad == 0) scrl[wq * 32 + j * 16 + l16] = acc_l[j][0];
      }
    }
    __syncthreads();
    if (grp == 0) {
#pragma unroll
      for (int j = 0; j < 2; ++j) {
        const int ql = wq * 32 + j * 16 + l16;
        const float inv = 1.0f / (acc_l[j][0] + scrl[ql]);
#pragma unroll
        for (int njo = 0; njo < 4; ++njo) {
          const int ch = (njo * 4 + quad) ^ l16;
          const f32x4 ob = *(const f32x4*)&scro[(size_t)ql * 64 + ch * 4];
          uint2 o;
          o.x = (unsigned)f2bf((acc_o[j][njo][0] + ob[0]) * inv) |
                ((unsigned)f2bf((acc_o[j][njo][1] + ob[1]) * inv) << 16);
          o.y = (unsigned)f2bf((acc_o[j][njo][2] + ob[2]) * inv) |
                ((unsigned)f2bf((acc_o[j][njo][3] + ob[3]) * inv) << 16);
          *(uint2*)&A2b[(size_t)(q0 + ql) * 64 + njo * 16 + quad * 4] = o;
        }
      }
    }
  }
}

// ---------------- launcher ----------------
extern "C" void kernel_launch(void* const* d_in, const int* in_sizes, int n_in,
                              void* d_out, int out_size, void* d_ws, size_t ws_size,
                              hipStream_t stream) {
  (void)in_sizes; (void)n_in; (void)out_size;
  const float* x  = (const float*)d_in[0];
  const float* Wq = (const float*)d_in[1];
  const float* Wk = (const float*)d_in[2];
  const float* Wv = (const float*)d_in[3];
  const float* Wo = (const float*)d_in[4];
  const float* bo = (const float*)d_in[5];
  float* out = (float*)d_out;
  char* ws = (char*)d_ws;
  const size_t MB = 1024 * 1024;
  const size_t KB = 1024;

  int hs = 2;
  if      (ws_size >= 2 * MB + 16 * 2432 * KB) hs = 16;
  else if (ws_size >= 2 * MB +  8 * 2432 * KB) hs = 8;
  else if (ws_size >= 2 * MB +  4 * 2432 * KB) hs = 4;

  u16* WoT   = (u16*)(ws);
  u16* Ksl   = (u16*)(ws + 2 * MB);
  u16* VTsl  = (u16*)(ws + 2 * MB + (size_t)hs *  512 * KB);
  u16* A2sl  = (u16*)(ws + 2 * MB + (size_t)hs * 1024 * KB);
  u16* WT3sl = (u16*)(ws + 2 * MB + (size_t)hs * 1536 * KB);
  u16* Qsl   = (u16*)(ws + 2 * MB + (size_t)hs * 1920 * KB);

  if (hs == 16) {
    u16* xb = A2sl;  // aliases A2sl: consumed by k2, overwritten by k3
    prep<<<dim3(144, 32), dim3(32, 32), 0, stream>>>(x, xb, Wq, Wk, Wv, Wo, WoT, WT3sl);
    gemm_bt<3, 0><<<dim3(24, 32), 256, 0, stream>>>(
        (const void*)xb, WT3sl, (void*)Qsl, Ksl, VTsl, nullptr, 4096, 3072, 1024, 16, 0);
    attn_fwd<<<dim3(512), 256, 0, stream>>>(Qsl, Ksl, VTsl, A2sl, 16);
    gemm_bt<1, 0><<<dim3(8, 32), 256, 0, stream>>>(
        (const void*)A2sl, WoT, (void*)out, nullptr, nullptr, bo, 4096, 1024, 1024, 16, 0);
  } else {
    transpose_cols<<<dim3(32, 32), dim3(32, 32), 0, stream>>>(Wo, Wo, Wo, WoT, 0, 1024);
    for (int h0 = 0; h0 < 16; h0 += hs) {
      transpose_cols<<<dim3(6 * hs, 32), dim3(32, 32), 0, stream>>>(Wq, Wk, Wv, WT3sl, h0, hs * 64);
      gemm_bt<3, 1><<<dim3((3 * hs) / 2, 32), 256, 0, stream>>>(
          (const void*)x, WT3sl, (void*)Qsl, Ksl, VTsl, nullptr, 4096, 3 * hs * 64, 1024, hs, h0);
      attn_fwd<<<dim3(16 * 2 * hs), 256, 0, stream>>>(Qsl, Ksl, VTsl, A2sl, hs);
      gemm_bt<1, 0><<<dim3(8, 2 * hs), 256, 0, stream>>>(
          (const void*)A2sl, WoT, (void*)out, nullptr, nullptr, bo, 2 * hs * 128, 1024, 1024, hs, h0);
    }
  }
}